// Round 4
// baseline (4749.420 us; speedup 1.0000x reference)
//
#include <hip/hip_runtime.h>

typedef unsigned short u16;
typedef unsigned int   u32;

#define N_NODES    15000
#define PADN       15008          // 469 * 32
#define N_EDGES    30000
#define NUM_GRAPHS 600
#define N_STEMS    6000
#define N_JBONDS   3000

// d_out flat layout: [0,1200) final, [1200,631200) stem_preds, [631200,634200) jbond
#define OUT_FINAL  0
#define OUT_STEM   1200
#define OUT_JB     631200

// K-extent of folded a1/M tensors: 64 real + 1 bias column + 7 zero pad = 72
#define KP 72
#define N_CVT 26
#define ECH 16                    // edge-partial chunk in k_fused

__device__ __forceinline__ float u2f(u16 v){ union{u32 i; float f;} c; c.i=((u32)v)<<16; return c.f; }
__device__ __forceinline__ u16  f2b(float f){ union{float f; u32 u;} c; c.f=f; u32 u=c.u;
                                              return (u16)((u + 0x7fffu + ((u>>16)&1u))>>16); }
__device__ __forceinline__ float lrelu(float x){ return x>0.f ? x : 0.01f*x; }
__device__ __forceinline__ float sigmoidf(float x){ return 1.f/(1.f+expf(-x)); }

__device__ __forceinline__ float dot64_f(const float* __restrict__ w, const float4* __restrict__ x4){
  const float4* wp = (const float4*)w;
  float acc = 0.f;
  #pragma unroll
  for(int c=0;c<16;c++){ float4 a=wp[c], b=x4[c]; acc += a.x*b.x+a.y*b.y+a.z*b.z+a.w*b.w; }
  return acc;
}

__device__ __forceinline__ int lower_bound_i(const int* __restrict__ a, int n, int v){
  int lo=0, hi=n;
  while(lo<hi){ int m=(lo+hi)>>1; if(a[m]<v) lo=m+1; else hi=m; }
  return lo;
}

__device__ __forceinline__ void store_out(void* dout, int isf, int idx, float v){
  if(isf) ((float*)dout)[idx] = v;
  else    ((u16*)dout)[idx]   = f2b(v);
}

// ---------------- dtype sniff: any bf16-NaN/Inf pattern => inputs are f32 ----------------
__global__ __launch_bounds__(256) void k_sniff(const u16* __restrict__ x, int n, int* __restrict__ flag){
  int i = blockIdx.x*256 + threadIdx.x;
  int local = 0;
  for(; i < n; i += gridDim.x*256){
    u16 v = x[i];
    if(((v>>7)&0xFFu) == 0xFFu) local = 1;
  }
  if(local) atomicOr(flag, 1);
}

// ---------------- convert all float inputs to f32 ----------------
struct CvtArgs { const void* src[N_CVT]; float* dst[N_CVT]; int n[N_CVT]; };

__global__ __launch_bounds__(256) void k_cvt(CvtArgs A, const int* __restrict__ flag){
  int isf = *flag;
  int tid = blockIdx.x*256 + threadIdx.x;
  int stride = gridDim.x*256;
  for(int b=0; b<N_CVT; b++){
    int n = A.n[b];
    const float* sf = (const float*)A.src[b];
    const u16*   sb = (const u16*)A.src[b];
    float* d = A.dst[b];
    for(int i=tid; i<n; i+=stride) d[i] = isf ? sf[i] : u2f(sb[i]);
  }
}

// ---------------- lin0 ----------------
__global__ __launch_bounds__(64) void k_lin0(const float* __restrict__ x, const float* __restrict__ w,
                                             const float* __restrict__ b,
                                             float* __restrict__ outF, float* __restrict__ hF){
  int n = blockIdx.x, o = threadIdx.x;
  __shared__ float xs[14];
  if(o<14) xs[o] = x[n*14+o];
  __syncthreads();
  float acc = b[o];
  #pragma unroll
  for(int i=0;i<14;i++) acc += xs[i]*w[o*14+i];
  acc = lrelu(acc);
  outF[n*64+o] = acc;
  hF[n*64+o]   = acc;
}

// ---------------- a1~[e][KP] ----------------
__global__ __launch_bounds__(128) void k_a1(const float* __restrict__ ea,
                                            const float* __restrict__ en1w, const float* __restrict__ en1b,
                                            float* __restrict__ a1){
  int e = blockIdx.x, k = threadIdx.x;
  if(k >= KP) return;
  float v;
  if(k < 64){
    float acc = en1b[k];
    #pragma unroll
    for(int c=0;c<4;c++) acc += ea[e*4+c] * en1w[k*4+c];
    v = lrelu(acc);
  } else v = (k==64) ? 1.0f : 0.0f;
  a1[(size_t)e*KP + k] = v;
}

// ---------------- W2f[j][k][o] ----------------
__global__ __launch_bounds__(256) void k_packW2(const float* __restrict__ en2w, const float* __restrict__ en2b,
                                                float* __restrict__ W2f){
  int idx = blockIdx.x*256 + threadIdx.x;
  if(idx >= 64*KP*64) return;
  int o = idx & 63;
  int r2 = idx >> 6;
  int k = r2 % KP;
  int j = r2 / KP;
  float v = 0.f;
  if(k < 64)       v = en2w[((size_t)(j*64+o))*64 + k];
  else if(k == 64) v = en2b[j*64+o];
  W2f[idx] = v;
}

// ---------------- rootT[o][j] = root_w[j][o] ----------------
__global__ __launch_bounds__(256) void k_rootT(const float* __restrict__ root, float* __restrict__ rootT){
  int i = blockIdx.x*256 + threadIdx.x;
  if(i < 4096){ int r=i>>6, c=i&63; rootT[c*64+r] = root[i]; }
}

// ---------------- deg/cnt ----------------
__global__ __launch_bounds__(256) void k_degcnt(const int* __restrict__ ei,
                                                float* __restrict__ deg, int* __restrict__ cnt){
  int e = blockIdx.x*256 + threadIdx.x;
  if(e < N_EDGES){
    atomicAdd(&deg[ei[N_EDGES + e]], 1.0f);
    atomicAdd(&cnt[ei[e]], 1);
  }
}

// ---------------- scan ----------------
__global__ __launch_bounds__(1024) void k_scan(const int* __restrict__ cnt,
                                               int* __restrict__ offs, int* __restrict__ pos){
  __shared__ int s[1024];
  int t = threadIdx.x;
  int base = t*15;
  int c[15];
  int loc = 0;
  #pragma unroll
  for(int i=0;i<15;i++){ int idx=base+i; int v=(idx<N_NODES)?cnt[idx]:0; c[i]=v; loc+=v; }
  s[t]=loc; __syncthreads();
  for(int d=1; d<1024; d<<=1){
    int v2 = (t>=d)? s[t-d] : 0;
    __syncthreads();
    s[t] += v2;
    __syncthreads();
  }
  int run = s[t]-loc;
  #pragma unroll
  for(int i=0;i<15;i++){
    int idx=base+i;
    if(idx<N_NODES){ offs[idx]=run; pos[idx]=run; }
    run += c[i];
  }
  if(t==1023) offs[N_NODES]=s[1023];
}

// ---------------- CSR fill ----------------
__global__ __launch_bounds__(256) void k_fill(const int* __restrict__ ei,
                                              int* __restrict__ pos, int* __restrict__ eidx){
  int e = blockIdx.x*256 + threadIdx.x;
  if(e < N_EDGES){
    int slot = atomicAdd(&pos[ei[e]], 1);
    eidx[slot] = e;
  }
}

// ---------------- fused M-build + message scatter (chunked reductions) ----------------
__global__ __launch_bounds__(512) void k_fused(const float* __restrict__ outF, const float* __restrict__ a1,
                                               const float* __restrict__ W2f,
                                               const int* __restrict__ ei_dst,
                                               const int* __restrict__ offs, const int* __restrict__ eidx,
                                               float* __restrict__ agg){
  int kc = threadIdx.x >> 6, o = threadIdx.x & 63;
  int nb = blockIdx.x * 8;
  __shared__ float outs[8][64];
  __shared__ float red[ECH][8][64];    // 32 KB edge-partial staging
  __shared__ int   edst[ECH];
  outs[kc][o] = outF[(nb+kc)*64 + o];
  __syncthreads();

  float Macc[8][9];
  #pragma unroll
  for(int n=0;n<8;n++)
    #pragma unroll
    for(int i=0;i<9;i++) Macc[n][i] = 0.f;

  for(int j=0;j<64;j++){
    const float* wr = W2f + ((size_t)j*KP + kc*9)*64 + o;
    float wv[9];
    #pragma unroll
    for(int i=0;i<9;i++) wv[i] = wr[i*64];
    #pragma unroll
    for(int n=0;n<8;n++){
      float oj = outs[n][j];
      #pragma unroll
      for(int i=0;i<9;i++) Macc[n][i] += oj * wv[i];
    }
  }

  int s = 0;
  #pragma unroll
  for(int n=0;n<8;n++){
    int node = nb + n;
    int lo = offs[node], hi = offs[node+1];   // block-uniform
    for(int t=lo; t<hi; t++){
      int e = eidx[t];
      int dst = ei_dst[e];
      const float* ap = a1 + (size_t)e*KP + kc*9;
      float p = 0.f;
      #pragma unroll
      for(int i=0;i<9;i++) p += ap[i] * Macc[n][i];
      red[s][kc][o] = p;
      if(threadIdx.x == 0) edst[s] = dst;
      s++;
      if(s == ECH){
        __syncthreads();
        for(int es=kc; es<s; es+=8){
          float v = red[es][0][o]+red[es][1][o]+red[es][2][o]+red[es][3][o]
                  + red[es][4][o]+red[es][5][o]+red[es][6][o]+red[es][7][o];
          atomicAdd(&agg[edst[es]*64 + o], v);
        }
        __syncthreads();
        s = 0;
      }
    }
  }
  if(s > 0){
    __syncthreads();
    for(int es=kc; es<s; es+=8){
      float v = red[es][0][o]+red[es][1][o]+red[es][2][o]+red[es][3][o]
              + red[es][4][o]+red[es][5][o]+red[es][6][o]+red[es][7][o];
      atomicAdd(&agg[edst[es]*64 + o], v);
    }
  }
}

// ---------------- node update v2: 32 nodes/block, 8 nodes/thread register blocking ----------------
// thread (o = tid&63, g = tid>>6): channel o, nodes g*8 .. g*8+7
__global__ __launch_bounds__(256) void k_node(const float* __restrict__ agg, const float* __restrict__ deg,
                                              float* __restrict__ outF, float* __restrict__ hF,
                                              const float* __restrict__ rootT, const float* __restrict__ convb,
                                              const float* __restrict__ wih, const float* __restrict__ whh,
                                              const float* __restrict__ bih, const float* __restrict__ bhh){
  int o = threadIdx.x & 63, g = threadIdx.x >> 6;
  int nb = blockIdx.x * 32;
  __shared__ __align__(16) float outs[32][64], hs[32][64], ms[32][64];

  // stage node state (padded buffers -> no read guards needed)
  for(int i=threadIdx.x; i<32*16; i+=256){
    ((float4*)outs)[i] = ((const float4*)(outF + (size_t)nb*64))[i];
    ((float4*)hs)[i]   = ((const float4*)(hF   + (size_t)nb*64))[i];
  }
  __syncthreads();

  // Phase A: m = lrelu(agg/deg + out @ root_w + conv_b) for 8 nodes
  float acc[8];
  float cb = convb[o];
  #pragma unroll
  for(int i=0;i<8;i++){
    int node = nb + g*8 + i;
    acc[i] = agg[(size_t)node*64 + o] / fmaxf(deg[node], 1.0f) + cb;
  }
  {
    const float4* rp = (const float4*)(rootT + o*64);
    #pragma unroll
    for(int c=0;c<16;c++){
      float4 w = rp[c];
      #pragma unroll
      for(int i=0;i<8;i++){
        float4 v = *(const float4*)&outs[g*8+i][c*4];
        acc[i] += v.x*w.x + v.y*w.y + v.z*w.z + v.w*w.w;
      }
    }
  }
  #pragma unroll
  for(int i=0;i<8;i++) ms[g*8+i][o] = lrelu(acc[i]);
  __syncthreads();

  // Phase B: GRU gates for 8 nodes
  float ir[8], iz[8], in_[8], hr[8], hz[8], hn[8];
  {
    float b0=bih[o], b1=bih[64+o], b2=bih[128+o];
    float c0=bhh[o], c1=bhh[64+o], c2=bhh[128+o];
    #pragma unroll
    for(int i=0;i<8;i++){ ir[i]=b0; iz[i]=b1; in_[i]=b2; hr[i]=c0; hz[i]=c1; hn[i]=c2; }
  }
  {
    const float4* w0 = (const float4*)(wih + (size_t)o*64);
    const float4* w1 = (const float4*)(wih + (size_t)(64+o)*64);
    const float4* w2 = (const float4*)(wih + (size_t)(128+o)*64);
    const float4* u0 = (const float4*)(whh + (size_t)o*64);
    const float4* u1 = (const float4*)(whh + (size_t)(64+o)*64);
    const float4* u2 = (const float4*)(whh + (size_t)(128+o)*64);
    #pragma unroll
    for(int c=0;c<16;c++){
      float4 a0=w0[c], a1v=w1[c], a2=w2[c], d0=u0[c], d1=u1[c], d2=u2[c];
      #pragma unroll
      for(int i=0;i<8;i++){
        float4 m4 = *(const float4*)&ms[g*8+i][c*4];
        float4 h4 = *(const float4*)&hs[g*8+i][c*4];
        ir[i]  += m4.x*a0.x + m4.y*a0.y + m4.z*a0.z + m4.w*a0.w;
        iz[i]  += m4.x*a1v.x+ m4.y*a1v.y+ m4.z*a1v.z+ m4.w*a1v.w;
        in_[i] += m4.x*a2.x + m4.y*a2.y + m4.z*a2.z + m4.w*a2.w;
        hr[i]  += h4.x*d0.x + h4.y*d0.y + h4.z*d0.z + h4.w*d0.w;
        hz[i]  += h4.x*d1.x + h4.y*d1.y + h4.z*d1.z + h4.w*d1.w;
        hn[i]  += h4.x*d2.x + h4.y*d2.y + h4.z*d2.z + h4.w*d2.w;
      }
    }
  }
  #pragma unroll
  for(int i=0;i<8;i++){
    int node = nb + g*8 + i;
    float r  = sigmoidf(ir[i] + hr[i]);
    float z  = sigmoidf(iz[i] + hz[i]);
    float ng = tanhf(in_[i] + r*hn[i]);
    float hnew = (1.f - z)*ng + z*hs[g*8+i][o];
    if(node < N_NODES){
      hF[(size_t)node*64 + o]   = hnew;
      outF[(size_t)node*64 + o] = hnew;
    }
  }
}

// ---------------- stem head ----------------
__global__ __launch_bounds__(128) void k_stem(const float* __restrict__ outF, const int* __restrict__ sidx,
                                              const float* __restrict__ s1w, const float* __restrict__ s1b,
                                              const float* __restrict__ s2w, const float* __restrict__ s2b,
                                              void* __restrict__ dout, const int* __restrict__ flag){
  int s = blockIdx.x, t = threadIdx.x;
  int isf = *flag;
  __shared__ __align__(16) float xs[64], hid[64];
  int a = sidx[s];
  if(t<64) xs[t] = outF[a*64+t];
  __syncthreads();
  if(t<64) hid[t] = lrelu(s1b[t] + dot64_f(s1w + t*64, (const float4*)xs));
  __syncthreads();
  if(t<105){
    float acc = s2b[t] + dot64_f(s2w + t*64, (const float4*)hid);
    store_out(dout, isf, OUT_STEM + s*105 + t, acc);
  }
}

// ---------------- jbond head ----------------
__global__ __launch_bounds__(128) void k_jbond(const float* __restrict__ outF, const int* __restrict__ jidx,
                                               const float* __restrict__ j1w, const float* __restrict__ j1b,
                                               const float* __restrict__ j2w, const float* __restrict__ j2b,
                                               void* __restrict__ dout, const int* __restrict__ flag){
  int jb = blockIdx.x, t = threadIdx.x;
  int isf = *flag;
  __shared__ __align__(16) float xs[2][64], hid[2][64];
  int at = t>>6, k = t&63;
  int a = jidx[jb*2 + at];
  xs[at][k] = outF[a*64+k];
  __syncthreads();
  hid[at][k] = lrelu(j1b[k] + dot64_f(j1w + k*64, (const float4*)xs[at]));
  __syncthreads();
  if(t<64){
    float p = (hid[0][t] + hid[1][t]) * j2w[t];
    #pragma unroll
    for(int s=32;s;s>>=1) p += __shfl_xor(p, s, 64);
    if(t==0) store_out(dout, isf, OUT_JB + jb, 0.5f*p + j2b[0]);
  }
}

// ---------------- Set2Set + final linear ----------------
__global__ __launch_bounds__(64) void k_s2s(const float* __restrict__ outF, const int* __restrict__ batch,
                                            const float* __restrict__ bih, const float* __restrict__ bhh,
                                            const float* __restrict__ loutw, const float* __restrict__ loutb,
                                            void* __restrict__ dout, const int* __restrict__ flag){
  int b = blockIdx.x, t = threadIdx.x;
  int isf = *flag;
  float i_ = bih[t]     + bhh[t];
  float g_ = bih[128+t] + bhh[128+t];
  float o_ = bih[192+t] + bhh[192+t];
  float c  = sigmoidf(i_)*tanhf(g_);
  float q  = sigmoidf(o_)*tanhf(c);

  int lo = lower_bound_i(batch, N_NODES, b);
  int hi = lower_bound_i(batch, N_NODES, b+1);

  float emax = -3.4e38f;
  for(int n=lo;n<hi;n++){
    float p = outF[n*64+t]*q;
    #pragma unroll
    for(int s=32;s;s>>=1) p += __shfl_xor(p, s, 64);
    emax = fmaxf(emax, p);
  }
  float Z = 0.f, racc = 0.f;
  for(int n=lo;n<hi;n++){
    float v = outF[n*64+t];
    float p = v*q;
    #pragma unroll
    for(int s=32;s;s>>=1) p += __shfl_xor(p, s, 64);
    float w = expf(p - emax);
    Z += w; racc += w*v;
  }
  float rp = (hi>lo) ? racc/Z : 0.f;

  #pragma unroll
  for(int j=0;j<2;j++){
    float p = q*loutw[j*128+t] + rp*loutw[j*128+64+t];
    #pragma unroll
    for(int s=32;s;s>>=1) p += __shfl_xor(p, s, 64);
    if(t==0) store_out(dout, isf, OUT_FINAL + b*2 + j, p + loutb[j]);
  }
}

extern "C" void kernel_launch(void* const* d_in, const int* in_sizes, int n_in,
                              void* d_out, int out_size, void* d_ws, size_t ws_size,
                              hipStream_t stream) {
  const int* edge_index  = (const int*)d_in[28];
  const int* stem_atmidx = (const int*)d_in[29];
  const int* jbond_atmidx= (const int*)d_in[30];
  const int* batch       = (const int*)d_in[31];

  char* ws = (char*)d_ws;
  size_t off = 0;
  auto alloc = [&](size_t bytes)->void*{ void* p = ws + off; off = (off + bytes + 255) & ~(size_t)255; return p; };

  int*   flag = (int*)  alloc(4);
  float* outF = (float*)alloc((size_t)PADN*64*4);
  float* hF   = (float*)alloc((size_t)PADN*64*4);
  float* agg  = (float*)alloc((size_t)PADN*64*4);
  float* a1   = (float*)alloc((size_t)N_EDGES*KP*4);
  float* W2f  = (float*)alloc((size_t)64*KP*64*4);
  float* deg  = (float*)alloc((size_t)PADN*4);
  int*   cnt  = (int*)  alloc((size_t)N_NODES*4);
  int*   offs = (int*)  alloc((size_t)(N_NODES+1)*4);
  int*   pos  = (int*)  alloc((size_t)N_NODES*4);
  int*   eidx = (int*)  alloc((size_t)N_EDGES*4);
  float* rootT= (float*)alloc(4096*4);

  static const int cvt_idx[N_CVT] = {0,1,2,3,4,5,6,7,8,9,10,11,12,13,14,15,16,17,18,19,20,21,24,25,26,27};
  CvtArgs A;
  float* cF[N_CVT];
  for(int i=0;i<N_CVT;i++){
    int src = cvt_idx[i];
    int n = in_sizes[src];
    cF[i] = (float*)alloc((size_t)n*4);
    A.src[i] = d_in[src];
    A.dst[i] = cF[i];
    A.n[i]   = n;
  }
  (void)ws_size; (void)n_in; (void)out_size;
  float* xF=cF[0];   float* eaF=cF[1];  float* l0w=cF[2];  float* l0b=cF[3];
  float* e1w=cF[4];  float* e1b=cF[5];  float* e2w=cF[6];  float* e2b=cF[7];
  float* rootw=cF[8];float* convb=cF[9];
  float* wih=cF[10]; float* whh=cF[11]; float* bih=cF[12]; float* bhh=cF[13];
  float* s1w=cF[14]; float* s1b=cF[15]; float* s2w=cF[16]; float* s2b=cF[17];
  float* j1w=cF[18]; float* j1b=cF[19]; float* j2w=cF[20]; float* j2b=cF[21];
  float* lbih=cF[22];float* lbhh=cF[23];float* loutw=cF[24];float* loutb=cF[25];

  hipMemsetAsync(flag, 0, 4, stream);
  hipMemsetAsync(deg,  0, (size_t)PADN*4, stream);
  hipMemsetAsync(cnt,  0, (size_t)N_NODES*4, stream);
  // pad tails of node state so padded blocks read defined values
  hipMemsetAsync(outF + (size_t)N_NODES*64, 0, (size_t)(PADN-N_NODES)*64*4, stream);
  hipMemsetAsync(hF   + (size_t)N_NODES*64, 0, (size_t)(PADN-N_NODES)*64*4, stream);

  k_sniff <<<128, 256, 0, stream>>>((const u16*)d_in[0], in_sizes[0], flag);
  k_cvt   <<<512, 256, 0, stream>>>(A, flag);

  k_lin0  <<<N_NODES, 64, 0, stream>>>(xF, l0w, l0b, outF, hF);
  k_a1    <<<N_EDGES, 128, 0, stream>>>(eaF, e1w, e1b, a1);
  k_packW2<<<(64*KP*64+255)/256, 256, 0, stream>>>(e2w, e2b, W2f);
  k_rootT <<<16, 256, 0, stream>>>(rootw, rootT);
  k_degcnt<<<(N_EDGES+255)/256, 256, 0, stream>>>(edge_index, deg, cnt);
  k_scan  <<<1, 1024, 0, stream>>>(cnt, offs, pos);
  k_fill  <<<(N_EDGES+255)/256, 256, 0, stream>>>(edge_index, pos, eidx);

  for(int it=0; it<6; it++){
    hipMemsetAsync(agg, 0, (size_t)PADN*64*4, stream);
    k_fused<<<N_NODES/8, 512, 0, stream>>>(outF, a1, W2f, edge_index + N_EDGES, offs, eidx, agg);
    k_node <<<PADN/32, 256, 0, stream>>>(agg, deg, outF, hF, rootT, convb, wih, whh, bih, bhh);
  }

  k_stem <<<N_STEMS, 128, 0, stream>>>(outF, stem_atmidx, s1w, s1b, s2w, s2b, d_out, flag);
  k_jbond<<<N_JBONDS, 128, 0, stream>>>(outF, jbond_atmidx, j1w, j1b, j2w, j2b, d_out, flag);
  k_s2s  <<<NUM_GRAPHS, 64, 0, stream>>>(outF, batch, lbih, lbhh, loutw, loutb, d_out, flag);
}

// Round 5
// 3656.279 us; speedup vs baseline: 1.2990x; 1.2990x over previous
//
#include <hip/hip_runtime.h>

typedef unsigned short u16;
typedef unsigned int   u32;

#define N_NODES    15000
#define PADN       15008          // 938 * 16
#define N_EDGES    30000
#define NUM_GRAPHS 600
#define N_STEMS    6000
#define N_JBONDS   3000

// d_out flat layout: [0,1200) final, [1200,631200) stem_preds, [631200,634200) jbond
#define OUT_FINAL  0
#define OUT_STEM   1200
#define OUT_JB     631200

// K-extent of folded a1/M tensors: 64 real + 1 bias column + 7 zero pad = 72
#define KP 72
#define N_CVT 26
#define ECH 16                    // edge-partial chunk in k_fused

__device__ __forceinline__ float u2f(u16 v){ union{u32 i; float f;} c; c.i=((u32)v)<<16; return c.f; }
__device__ __forceinline__ u16  f2b(float f){ union{float f; u32 u;} c; c.f=f; u32 u=c.u;
                                              return (u16)((u + 0x7fffu + ((u>>16)&1u))>>16); }
__device__ __forceinline__ float lrelu(float x){ return x>0.f ? x : 0.01f*x; }
__device__ __forceinline__ float sigmoidf(float x){ return 1.f/(1.f+expf(-x)); }

__device__ __forceinline__ float dot64_f(const float* __restrict__ w, const float4* __restrict__ x4){
  const float4* wp = (const float4*)w;
  float acc = 0.f;
  #pragma unroll
  for(int c=0;c<16;c++){ float4 a=wp[c], b=x4[c]; acc += a.x*b.x+a.y*b.y+a.z*b.z+a.w*b.w; }
  return acc;
}

__device__ __forceinline__ int lower_bound_i(const int* __restrict__ a, int n, int v){
  int lo=0, hi=n;
  while(lo<hi){ int m=(lo+hi)>>1; if(a[m]<v) lo=m+1; else hi=m; }
  return lo;
}

__device__ __forceinline__ void store_out(void* dout, int isf, int idx, float v){
  if(isf) ((float*)dout)[idx] = v;
  else    ((u16*)dout)[idx]   = f2b(v);
}

// ---------------- dtype sniff: any bf16-NaN/Inf pattern => inputs are f32 ----------------
__global__ __launch_bounds__(256) void k_sniff(const u16* __restrict__ x, int n, int* __restrict__ flag){
  int i = blockIdx.x*256 + threadIdx.x;
  int local = 0;
  for(; i < n; i += gridDim.x*256){
    u16 v = x[i];
    if(((v>>7)&0xFFu) == 0xFFu) local = 1;
  }
  if(local) atomicOr(flag, 1);
}

// ---------------- convert all float inputs to f32 ----------------
struct CvtArgs { const void* src[N_CVT]; float* dst[N_CVT]; int n[N_CVT]; };

__global__ __launch_bounds__(256) void k_cvt(CvtArgs A, const int* __restrict__ flag){
  int isf = *flag;
  int tid = blockIdx.x*256 + threadIdx.x;
  int stride = gridDim.x*256;
  for(int b=0; b<N_CVT; b++){
    int n = A.n[b];
    const float* sf = (const float*)A.src[b];
    const u16*   sb = (const u16*)A.src[b];
    float* d = A.dst[b];
    for(int i=tid; i<n; i+=stride) d[i] = isf ? sf[i] : u2f(sb[i]);
  }
}

// ---------------- lin0 ----------------
__global__ __launch_bounds__(64) void k_lin0(const float* __restrict__ x, const float* __restrict__ w,
                                             const float* __restrict__ b,
                                             float* __restrict__ outF, float* __restrict__ hF){
  int n = blockIdx.x, o = threadIdx.x;
  __shared__ float xs[14];
  if(o<14) xs[o] = x[n*14+o];
  __syncthreads();
  float acc = b[o];
  #pragma unroll
  for(int i=0;i<14;i++) acc += xs[i]*w[o*14+i];
  acc = lrelu(acc);
  outF[n*64+o] = acc;
  hF[n*64+o]   = acc;
}

// ---------------- a1~[e][KP] ----------------
__global__ __launch_bounds__(128) void k_a1(const float* __restrict__ ea,
                                            const float* __restrict__ en1w, const float* __restrict__ en1b,
                                            float* __restrict__ a1){
  int e = blockIdx.x, k = threadIdx.x;
  if(k >= KP) return;
  float v;
  if(k < 64){
    float acc = en1b[k];
    #pragma unroll
    for(int c=0;c<4;c++) acc += ea[e*4+c] * en1w[k*4+c];
    v = lrelu(acc);
  } else v = (k==64) ? 1.0f : 0.0f;
  a1[(size_t)e*KP + k] = v;
}

// ---------------- W2f[j][k][o] ----------------
__global__ __launch_bounds__(256) void k_packW2(const float* __restrict__ en2w, const float* __restrict__ en2b,
                                                float* __restrict__ W2f){
  int idx = blockIdx.x*256 + threadIdx.x;
  if(idx >= 64*KP*64) return;
  int o = idx & 63;
  int r2 = idx >> 6;
  int k = r2 % KP;
  int j = r2 / KP;
  float v = 0.f;
  if(k < 64)       v = en2w[((size_t)(j*64+o))*64 + k];
  else if(k == 64) v = en2b[j*64+o];
  W2f[idx] = v;
}

// ---------------- rootT[o][j] = root_w[j][o] ----------------
__global__ __launch_bounds__(256) void k_rootT(const float* __restrict__ root, float* __restrict__ rootT){
  int i = blockIdx.x*256 + threadIdx.x;
  if(i < 4096){ int r=i>>6, c=i&63; rootT[c*64+r] = root[i]; }
}

// ---------------- deg/cnt ----------------
__global__ __launch_bounds__(256) void k_degcnt(const int* __restrict__ ei,
                                                float* __restrict__ deg, int* __restrict__ cnt){
  int e = blockIdx.x*256 + threadIdx.x;
  if(e < N_EDGES){
    atomicAdd(&deg[ei[N_EDGES + e]], 1.0f);
    atomicAdd(&cnt[ei[e]], 1);
  }
}

// ---------------- scan ----------------
__global__ __launch_bounds__(1024) void k_scan(const int* __restrict__ cnt,
                                               int* __restrict__ offs, int* __restrict__ pos){
  __shared__ int s[1024];
  int t = threadIdx.x;
  int base = t*15;
  int c[15];
  int loc = 0;
  #pragma unroll
  for(int i=0;i<15;i++){ int idx=base+i; int v=(idx<N_NODES)?cnt[idx]:0; c[i]=v; loc+=v; }
  s[t]=loc; __syncthreads();
  for(int d=1; d<1024; d<<=1){
    int v2 = (t>=d)? s[t-d] : 0;
    __syncthreads();
    s[t] += v2;
    __syncthreads();
  }
  int run = s[t]-loc;
  #pragma unroll
  for(int i=0;i<15;i++){
    int idx=base+i;
    if(idx<N_NODES){ offs[idx]=run; pos[idx]=run; }
    run += c[i];
  }
  if(t==1023) offs[N_NODES]=s[1023];
}

// ---------------- CSR fill ----------------
__global__ __launch_bounds__(256) void k_fill(const int* __restrict__ ei,
                                              int* __restrict__ pos, int* __restrict__ eidx){
  int e = blockIdx.x*256 + threadIdx.x;
  if(e < N_EDGES){
    int slot = atomicAdd(&pos[ei[e]], 1);
    eidx[slot] = e;
  }
}

// ---------------- fused M-build + message scatter (chunked reductions) ----------------
__global__ __launch_bounds__(512) void k_fused(const float* __restrict__ outF, const float* __restrict__ a1,
                                               const float* __restrict__ W2f,
                                               const int* __restrict__ ei_dst,
                                               const int* __restrict__ offs, const int* __restrict__ eidx,
                                               float* __restrict__ agg){
  int kc = threadIdx.x >> 6, o = threadIdx.x & 63;
  int nb = blockIdx.x * 8;
  __shared__ float outs[8][64];
  __shared__ float red[ECH][8][64];    // 32 KB edge-partial staging
  __shared__ int   edst[ECH];
  outs[kc][o] = outF[(nb+kc)*64 + o];
  __syncthreads();

  float Macc[8][9];
  #pragma unroll
  for(int n=0;n<8;n++)
    #pragma unroll
    for(int i=0;i<9;i++) Macc[n][i] = 0.f;

  for(int j=0;j<64;j++){
    const float* wr = W2f + ((size_t)j*KP + kc*9)*64 + o;
    float wv[9];
    #pragma unroll
    for(int i=0;i<9;i++) wv[i] = wr[i*64];
    #pragma unroll
    for(int n=0;n<8;n++){
      float oj = outs[n][j];
      #pragma unroll
      for(int i=0;i<9;i++) Macc[n][i] += oj * wv[i];
    }
  }

  int s = 0;
  #pragma unroll
  for(int n=0;n<8;n++){
    int node = nb + n;
    int lo = offs[node], hi = offs[node+1];   // block-uniform
    for(int t=lo; t<hi; t++){
      int e = eidx[t];
      int dst = ei_dst[e];
      const float* ap = a1 + (size_t)e*KP + kc*9;
      float p = 0.f;
      #pragma unroll
      for(int i=0;i<9;i++) p += ap[i] * Macc[n][i];
      red[s][kc][o] = p;
      if(threadIdx.x == 0) edst[s] = dst;
      s++;
      if(s == ECH){
        __syncthreads();
        for(int es=kc; es<s; es+=8){
          float v = red[es][0][o]+red[es][1][o]+red[es][2][o]+red[es][3][o]
                  + red[es][4][o]+red[es][5][o]+red[es][6][o]+red[es][7][o];
          atomicAdd(&agg[edst[es]*64 + o], v);
        }
        __syncthreads();
        s = 0;
      }
    }
  }
  if(s > 0){
    __syncthreads();
    for(int es=kc; es<s; es+=8){
      float v = red[es][0][o]+red[es][1][o]+red[es][2][o]+red[es][3][o]
              + red[es][4][o]+red[es][5][o]+red[es][6][o]+red[es][7][o];
      atomicAdd(&agg[edst[es]*64 + o], v);
    }
  }
}

// ---------------- node update v3: 16 nodes/block, 4 nodes/thread (spill-safe) ----------------
// thread (o = tid&63, g = tid>>6): channel o, nodes g*4 .. g*4+3
__global__ __launch_bounds__(256) void k_node(const float* __restrict__ agg, const float* __restrict__ deg,
                                              float* __restrict__ outF, float* __restrict__ hF,
                                              const float* __restrict__ rootT, const float* __restrict__ convb,
                                              const float* __restrict__ wih, const float* __restrict__ whh,
                                              const float* __restrict__ bih, const float* __restrict__ bhh){
  int o = threadIdx.x & 63, g = threadIdx.x >> 6;
  int nb = blockIdx.x * 16;
  __shared__ __align__(16) float outs[16][64], hs[16][64], ms[16][64];

  // stage node state (padded buffers -> no read guards needed)
  for(int i=threadIdx.x; i<16*16; i+=256){
    ((float4*)outs)[i] = ((const float4*)(outF + (size_t)nb*64))[i];
    ((float4*)hs)[i]   = ((const float4*)(hF   + (size_t)nb*64))[i];
  }
  __syncthreads();

  // Phase A: m = lrelu(agg/deg + out @ root_w + conv_b) for 4 nodes
  float acc[4];
  float cb = convb[o];
  #pragma unroll
  for(int i=0;i<4;i++){
    int node = nb + g*4 + i;
    acc[i] = agg[(size_t)node*64 + o] / fmaxf(deg[node], 1.0f) + cb;
  }
  {
    const float4* rp = (const float4*)(rootT + o*64);
    #pragma unroll
    for(int c=0;c<16;c++){
      float4 w = rp[c];
      #pragma unroll
      for(int i=0;i<4;i++){
        float4 v = *(const float4*)&outs[g*4+i][c*4];
        acc[i] += v.x*w.x + v.y*w.y + v.z*w.z + v.w*w.w;
      }
    }
  }
  #pragma unroll
  for(int i=0;i<4;i++) ms[g*4+i][o] = lrelu(acc[i]);
  __syncthreads();

  // Phase B: GRU gates for 4 nodes
  float ir[4], iz[4], in_[4], hr[4], hz[4], hn[4];
  {
    float b0=bih[o], b1=bih[64+o], b2=bih[128+o];
    float c0=bhh[o], c1=bhh[64+o], c2=bhh[128+o];
    #pragma unroll
    for(int i=0;i<4;i++){ ir[i]=b0; iz[i]=b1; in_[i]=b2; hr[i]=c0; hz[i]=c1; hn[i]=c2; }
  }
  {
    const float4* w0 = (const float4*)(wih + (size_t)o*64);
    const float4* w1 = (const float4*)(wih + (size_t)(64+o)*64);
    const float4* w2 = (const float4*)(wih + (size_t)(128+o)*64);
    const float4* u0 = (const float4*)(whh + (size_t)o*64);
    const float4* u1 = (const float4*)(whh + (size_t)(64+o)*64);
    const float4* u2 = (const float4*)(whh + (size_t)(128+o)*64);
    #pragma unroll
    for(int c=0;c<16;c++){
      float4 a0=w0[c], a1v=w1[c], a2=w2[c], d0=u0[c], d1=u1[c], d2=u2[c];
      #pragma unroll
      for(int i=0;i<4;i++){
        float4 m4 = *(const float4*)&ms[g*4+i][c*4];
        float4 h4 = *(const float4*)&hs[g*4+i][c*4];
        ir[i]  += m4.x*a0.x + m4.y*a0.y + m4.z*a0.z + m4.w*a0.w;
        iz[i]  += m4.x*a1v.x+ m4.y*a1v.y+ m4.z*a1v.z+ m4.w*a1v.w;
        in_[i] += m4.x*a2.x + m4.y*a2.y + m4.z*a2.z + m4.w*a2.w;
        hr[i]  += h4.x*d0.x + h4.y*d0.y + h4.z*d0.z + h4.w*d0.w;
        hz[i]  += h4.x*d1.x + h4.y*d1.y + h4.z*d1.z + h4.w*d1.w;
        hn[i]  += h4.x*d2.x + h4.y*d2.y + h4.z*d2.z + h4.w*d2.w;
      }
    }
  }
  #pragma unroll
  for(int i=0;i<4;i++){
    int node = nb + g*4 + i;
    float r  = sigmoidf(ir[i] + hr[i]);
    float z  = sigmoidf(iz[i] + hz[i]);
    float ng = tanhf(in_[i] + r*hn[i]);
    float hnew = (1.f - z)*ng + z*hs[g*4+i][o];
    if(node < N_NODES){
      hF[(size_t)node*64 + o]   = hnew;
      outF[(size_t)node*64 + o] = hnew;
    }
  }
}

// ---------------- stem head ----------------
__global__ __launch_bounds__(128) void k_stem(const float* __restrict__ outF, const int* __restrict__ sidx,
                                              const float* __restrict__ s1w, const float* __restrict__ s1b,
                                              const float* __restrict__ s2w, const float* __restrict__ s2b,
                                              void* __restrict__ dout, const int* __restrict__ flag){
  int s = blockIdx.x, t = threadIdx.x;
  int isf = *flag;
  __shared__ __align__(16) float xs[64], hid[64];
  int a = sidx[s];
  if(t<64) xs[t] = outF[a*64+t];
  __syncthreads();
  if(t<64) hid[t] = lrelu(s1b[t] + dot64_f(s1w + t*64, (const float4*)xs));
  __syncthreads();
  if(t<105){
    float acc = s2b[t] + dot64_f(s2w + t*64, (const float4*)hid);
    store_out(dout, isf, OUT_STEM + s*105 + t, acc);
  }
}

// ---------------- jbond head ----------------
__global__ __launch_bounds__(128) void k_jbond(const float* __restrict__ outF, const int* __restrict__ jidx,
                                               const float* __restrict__ j1w, const float* __restrict__ j1b,
                                               const float* __restrict__ j2w, const float* __restrict__ j2b,
                                               void* __restrict__ dout, const int* __restrict__ flag){
  int jb = blockIdx.x, t = threadIdx.x;
  int isf = *flag;
  __shared__ __align__(16) float xs[2][64], hid[2][64];
  int at = t>>6, k = t&63;
  int a = jidx[jb*2 + at];
  xs[at][k] = outF[a*64+k];
  __syncthreads();
  hid[at][k] = lrelu(j1b[k] + dot64_f(j1w + k*64, (const float4*)xs[at]));
  __syncthreads();
  if(t<64){
    float p = (hid[0][t] + hid[1][t]) * j2w[t];
    #pragma unroll
    for(int s=32;s;s>>=1) p += __shfl_xor(p, s, 64);
    if(t==0) store_out(dout, isf, OUT_JB + jb, 0.5f*p + j2b[0]);
  }
}

// ---------------- Set2Set + final linear ----------------
__global__ __launch_bounds__(64) void k_s2s(const float* __restrict__ outF, const int* __restrict__ batch,
                                            const float* __restrict__ bih, const float* __restrict__ bhh,
                                            const float* __restrict__ loutw, const float* __restrict__ loutb,
                                            void* __restrict__ dout, const int* __restrict__ flag){
  int b = blockIdx.x, t = threadIdx.x;
  int isf = *flag;
  float i_ = bih[t]     + bhh[t];
  float g_ = bih[128+t] + bhh[128+t];
  float o_ = bih[192+t] + bhh[192+t];
  float c  = sigmoidf(i_)*tanhf(g_);
  float q  = sigmoidf(o_)*tanhf(c);

  int lo = lower_bound_i(batch, N_NODES, b);
  int hi = lower_bound_i(batch, N_NODES, b+1);

  float emax = -3.4e38f;
  for(int n=lo;n<hi;n++){
    float p = outF[n*64+t]*q;
    #pragma unroll
    for(int s=32;s;s>>=1) p += __shfl_xor(p, s, 64);
    emax = fmaxf(emax, p);
  }
  float Z = 0.f, racc = 0.f;
  for(int n=lo;n<hi;n++){
    float v = outF[n*64+t];
    float p = v*q;
    #pragma unroll
    for(int s=32;s;s>>=1) p += __shfl_xor(p, s, 64);
    float w = expf(p - emax);
    Z += w; racc += w*v;
  }
  float rp = (hi>lo) ? racc/Z : 0.f;

  #pragma unroll
  for(int j=0;j<2;j++){
    float p = q*loutw[j*128+t] + rp*loutw[j*128+64+t];
    #pragma unroll
    for(int s=32;s;s>>=1) p += __shfl_xor(p, s, 64);
    if(t==0) store_out(dout, isf, OUT_FINAL + b*2 + j, p + loutb[j]);
  }
}

extern "C" void kernel_launch(void* const* d_in, const int* in_sizes, int n_in,
                              void* d_out, int out_size, void* d_ws, size_t ws_size,
                              hipStream_t stream) {
  const int* edge_index  = (const int*)d_in[28];
  const int* stem_atmidx = (const int*)d_in[29];
  const int* jbond_atmidx= (const int*)d_in[30];
  const int* batch       = (const int*)d_in[31];

  char* ws = (char*)d_ws;
  size_t off = 0;
  auto alloc = [&](size_t bytes)->void*{ void* p = ws + off; off = (off + bytes + 255) & ~(size_t)255; return p; };

  int*   flag = (int*)  alloc(4);
  float* outF = (float*)alloc((size_t)PADN*64*4);
  float* hF   = (float*)alloc((size_t)PADN*64*4);
  float* agg  = (float*)alloc((size_t)PADN*64*4);
  float* a1   = (float*)alloc((size_t)N_EDGES*KP*4);
  float* W2f  = (float*)alloc((size_t)64*KP*64*4);
  float* deg  = (float*)alloc((size_t)PADN*4);
  int*   cnt  = (int*)  alloc((size_t)N_NODES*4);
  int*   offs = (int*)  alloc((size_t)(N_NODES+1)*4);
  int*   pos  = (int*)  alloc((size_t)N_NODES*4);
  int*   eidx = (int*)  alloc((size_t)N_EDGES*4);
  float* rootT= (float*)alloc(4096*4);

  static const int cvt_idx[N_CVT] = {0,1,2,3,4,5,6,7,8,9,10,11,12,13,14,15,16,17,18,19,20,21,24,25,26,27};
  CvtArgs A;
  float* cF[N_CVT];
  for(int i=0;i<N_CVT;i++){
    int src = cvt_idx[i];
    int n = in_sizes[src];
    cF[i] = (float*)alloc((size_t)n*4);
    A.src[i] = d_in[src];
    A.dst[i] = cF[i];
    A.n[i]   = n;
  }
  (void)ws_size; (void)n_in; (void)out_size;
  float* xF=cF[0];   float* eaF=cF[1];  float* l0w=cF[2];  float* l0b=cF[3];
  float* e1w=cF[4];  float* e1b=cF[5];  float* e2w=cF[6];  float* e2b=cF[7];
  float* rootw=cF[8];float* convb=cF[9];
  float* wih=cF[10]; float* whh=cF[11]; float* bih=cF[12]; float* bhh=cF[13];
  float* s1w=cF[14]; float* s1b=cF[15]; float* s2w=cF[16]; float* s2b=cF[17];
  float* j1w=cF[18]; float* j1b=cF[19]; float* j2w=cF[20]; float* j2b=cF[21];
  float* lbih=cF[22];float* lbhh=cF[23];float* loutw=cF[24];float* loutb=cF[25];

  hipMemsetAsync(flag, 0, 4, stream);
  hipMemsetAsync(deg,  0, (size_t)PADN*4, stream);
  hipMemsetAsync(cnt,  0, (size_t)N_NODES*4, stream);
  // pad tails of node state so padded blocks read defined values
  hipMemsetAsync(outF + (size_t)N_NODES*64, 0, (size_t)(PADN-N_NODES)*64*4, stream);
  hipMemsetAsync(hF   + (size_t)N_NODES*64, 0, (size_t)(PADN-N_NODES)*64*4, stream);

  k_sniff <<<128, 256, 0, stream>>>((const u16*)d_in[0], in_sizes[0], flag);
  k_cvt   <<<512, 256, 0, stream>>>(A, flag);

  k_lin0  <<<N_NODES, 64, 0, stream>>>(xF, l0w, l0b, outF, hF);
  k_a1    <<<N_EDGES, 128, 0, stream>>>(eaF, e1w, e1b, a1);
  k_packW2<<<(64*KP*64+255)/256, 256, 0, stream>>>(e2w, e2b, W2f);
  k_rootT <<<16, 256, 0, stream>>>(rootw, rootT);
  k_degcnt<<<(N_EDGES+255)/256, 256, 0, stream>>>(edge_index, deg, cnt);
  k_scan  <<<1, 1024, 0, stream>>>(cnt, offs, pos);
  k_fill  <<<(N_EDGES+255)/256, 256, 0, stream>>>(edge_index, pos, eidx);

  for(int it=0; it<6; it++){
    hipMemsetAsync(agg, 0, (size_t)PADN*64*4, stream);
    k_fused<<<N_NODES/8, 512, 0, stream>>>(outF, a1, W2f, edge_index + N_EDGES, offs, eidx, agg);
    k_node <<<PADN/16, 256, 0, stream>>>(agg, deg, outF, hF, rootT, convb, wih, whh, bih, bhh);
  }

  k_stem <<<N_STEMS, 128, 0, stream>>>(outF, stem_atmidx, s1w, s1b, s2w, s2b, d_out, flag);
  k_jbond<<<N_JBONDS, 128, 0, stream>>>(outF, jbond_atmidx, j1w, j1b, j2w, j2b, d_out, flag);
  k_s2s  <<<NUM_GRAPHS, 64, 0, stream>>>(outF, batch, lbih, lbhh, loutw, loutb, d_out, flag);
}

// Round 6
// 3051.160 us; speedup vs baseline: 1.5566x; 1.1983x over previous
//
#include <hip/hip_runtime.h>

typedef unsigned short u16;
typedef unsigned int   u32;

#define N_NODES    15000
#define PADN       15008          // multiple of 8 and 16
#define N_EDGES    30000
#define NUM_GRAPHS 600
#define N_STEMS    6000
#define N_JBONDS   3000

// d_out flat layout: [0,1200) final, [1200,631200) stem_preds, [631200,634200) jbond
#define OUT_FINAL  0
#define OUT_STEM   1200
#define OUT_JB     631200

// K-extent of folded a1/M tensors: 64 real + 1 bias column + 7 zero pad = 72
#define KP 72
#define N_CVT 26
#define ECH 16                    // edge-partial chunk in k_fused

__device__ __forceinline__ float u2f(u16 v){ union{u32 i; float f;} c; c.i=((u32)v)<<16; return c.f; }
__device__ __forceinline__ u16  f2b(float f){ union{float f; u32 u;} c; c.f=f; u32 u=c.u;
                                              return (u16)((u + 0x7fffu + ((u>>16)&1u))>>16); }
__device__ __forceinline__ float lrelu(float x){ return x>0.f ? x : 0.01f*x; }
__device__ __forceinline__ float sigmoidf(float x){ return 1.f/(1.f+expf(-x)); }

__device__ __forceinline__ float dot64_f(const float* __restrict__ w, const float4* __restrict__ x4){
  const float4* wp = (const float4*)w;
  float acc = 0.f;
  #pragma unroll
  for(int c=0;c<16;c++){ float4 a=wp[c], b=x4[c]; acc += a.x*b.x+a.y*b.y+a.z*b.z+a.w*b.w; }
  return acc;
}

__device__ __forceinline__ int lower_bound_i(const int* __restrict__ a, int n, int v){
  int lo=0, hi=n;
  while(lo<hi){ int m=(lo+hi)>>1; if(a[m]<v) lo=m+1; else hi=m; }
  return lo;
}

__device__ __forceinline__ void store_out(void* dout, int isf, int idx, float v){
  if(isf) ((float*)dout)[idx] = v;
  else    ((u16*)dout)[idx]   = f2b(v);
}

// ---------------- dtype sniff ----------------
__global__ __launch_bounds__(256) void k_sniff(const u16* __restrict__ x, int n, int* __restrict__ flag){
  int i = blockIdx.x*256 + threadIdx.x;
  int local = 0;
  for(; i < n; i += gridDim.x*256){
    u16 v = x[i];
    if(((v>>7)&0xFFu) == 0xFFu) local = 1;
  }
  if(local) atomicOr(flag, 1);
}

// ---------------- convert float inputs to f32 ----------------
struct CvtArgs { const void* src[N_CVT]; float* dst[N_CVT]; int n[N_CVT]; };

__global__ __launch_bounds__(256) void k_cvt(CvtArgs A, const int* __restrict__ flag){
  int isf = *flag;
  int tid = blockIdx.x*256 + threadIdx.x;
  int stride = gridDim.x*256;
  for(int b=0; b<N_CVT; b++){
    int n = A.n[b];
    const float* sf = (const float*)A.src[b];
    const u16*   sb = (const u16*)A.src[b];
    float* d = A.dst[b];
    for(int i=tid; i<n; i+=stride) d[i] = isf ? sf[i] : u2f(sb[i]);
  }
}

// ---------------- lin0 ----------------
__global__ __launch_bounds__(64) void k_lin0(const float* __restrict__ x, const float* __restrict__ w,
                                             const float* __restrict__ b,
                                             float* __restrict__ outF, float* __restrict__ hF){
  int n = blockIdx.x, o = threadIdx.x;
  __shared__ float xs[14];
  if(o<14) xs[o] = x[n*14+o];
  __syncthreads();
  float acc = b[o];
  #pragma unroll
  for(int i=0;i<14;i++) acc += xs[i]*w[o*14+i];
  acc = lrelu(acc);
  outF[n*64+o] = acc;
  hF[n*64+o]   = acc;
}

// ---------------- a1~[e][KP] ----------------
__global__ __launch_bounds__(128) void k_a1(const float* __restrict__ ea,
                                            const float* __restrict__ en1w, const float* __restrict__ en1b,
                                            float* __restrict__ a1){
  int e = blockIdx.x, k = threadIdx.x;
  if(k >= KP) return;
  float v;
  if(k < 64){
    float acc = en1b[k];
    #pragma unroll
    for(int c=0;c<4;c++) acc += ea[e*4+c] * en1w[k*4+c];
    v = lrelu(acc);
  } else v = (k==64) ? 1.0f : 0.0f;
  a1[(size_t)e*KP + k] = v;
}

// ---------------- W2f[j][k][o] ----------------
__global__ __launch_bounds__(256) void k_packW2(const float* __restrict__ en2w, const float* __restrict__ en2b,
                                                float* __restrict__ W2f){
  int idx = blockIdx.x*256 + threadIdx.x;
  if(idx >= 64*KP*64) return;
  int o = idx & 63;
  int r2 = idx >> 6;
  int k = r2 % KP;
  int j = r2 / KP;
  float v = 0.f;
  if(k < 64)       v = en2w[((size_t)(j*64+o))*64 + k];
  else if(k == 64) v = en2b[j*64+o];
  W2f[idx] = v;
}

// ---------------- rootT[o][j] = root_w[j][o] ----------------
__global__ __launch_bounds__(256) void k_rootT(const float* __restrict__ root, float* __restrict__ rootT){
  int i = blockIdx.x*256 + threadIdx.x;
  if(i < 4096){ int r=i>>6, c=i&63; rootT[c*64+r] = root[i]; }
}

// ---------------- deg/cnt ----------------
__global__ __launch_bounds__(256) void k_degcnt(const int* __restrict__ ei,
                                                float* __restrict__ deg, int* __restrict__ cnt){
  int e = blockIdx.x*256 + threadIdx.x;
  if(e < N_EDGES){
    atomicAdd(&deg[ei[N_EDGES + e]], 1.0f);
    atomicAdd(&cnt[ei[e]], 1);
  }
}

// ---------------- scan ----------------
__global__ __launch_bounds__(1024) void k_scan(const int* __restrict__ cnt,
                                               int* __restrict__ offs, int* __restrict__ pos){
  __shared__ int s[1024];
  int t = threadIdx.x;
  int base = t*15;
  int c[15];
  int loc = 0;
  #pragma unroll
  for(int i=0;i<15;i++){ int idx=base+i; int v=(idx<N_NODES)?cnt[idx]:0; c[i]=v; loc+=v; }
  s[t]=loc; __syncthreads();
  for(int d=1; d<1024; d<<=1){
    int v2 = (t>=d)? s[t-d] : 0;
    __syncthreads();
    s[t] += v2;
    __syncthreads();
  }
  int run = s[t]-loc;
  #pragma unroll
  for(int i=0;i<15;i++){
    int idx=base+i;
    if(idx<N_NODES){ offs[idx]=run; pos[idx]=run; }
    run += c[i];
  }
  if(t==1023) offs[N_NODES]=s[1023];
}

// ---------------- CSR fill ----------------
__global__ __launch_bounds__(256) void k_fill(const int* __restrict__ ei,
                                              int* __restrict__ pos, int* __restrict__ eidx){
  int e = blockIdx.x*256 + threadIdx.x;
  if(e < N_EDGES){
    int slot = atomicAdd(&pos[ei[e]], 1);
    eidx[slot] = e;
  }
}

// ---------------- fused M-build + message scatter (unchanged this round) ----------------
__global__ __launch_bounds__(512) void k_fused(const float* __restrict__ outF, const float* __restrict__ a1,
                                               const float* __restrict__ W2f,
                                               const int* __restrict__ ei_dst,
                                               const int* __restrict__ offs, const int* __restrict__ eidx,
                                               float* __restrict__ agg){
  int kc = threadIdx.x >> 6, o = threadIdx.x & 63;
  int nb = blockIdx.x * 8;
  __shared__ float outs[8][64];
  __shared__ float red[ECH][8][64];
  __shared__ int   edst[ECH];
  outs[kc][o] = outF[(nb+kc)*64 + o];
  __syncthreads();

  float Macc[8][9];
  #pragma unroll
  for(int n=0;n<8;n++)
    #pragma unroll
    for(int i=0;i<9;i++) Macc[n][i] = 0.f;

  for(int j=0;j<64;j++){
    const float* wr = W2f + ((size_t)j*KP + kc*9)*64 + o;
    float wv[9];
    #pragma unroll
    for(int i=0;i<9;i++) wv[i] = wr[i*64];
    #pragma unroll
    for(int n=0;n<8;n++){
      float oj = outs[n][j];
      #pragma unroll
      for(int i=0;i<9;i++) Macc[n][i] += oj * wv[i];
    }
  }

  int s = 0;
  #pragma unroll
  for(int n=0;n<8;n++){
    int node = nb + n;
    int lo = offs[node], hi = offs[node+1];
    for(int t=lo; t<hi; t++){
      int e = eidx[t];
      int dst = ei_dst[e];
      const float* ap = a1 + (size_t)e*KP + kc*9;
      float p = 0.f;
      #pragma unroll
      for(int i=0;i<9;i++) p += ap[i] * Macc[n][i];
      red[s][kc][o] = p;
      if(threadIdx.x == 0) edst[s] = dst;
      s++;
      if(s == ECH){
        __syncthreads();
        for(int es=kc; es<s; es+=8){
          float v = red[es][0][o]+red[es][1][o]+red[es][2][o]+red[es][3][o]
                  + red[es][4][o]+red[es][5][o]+red[es][6][o]+red[es][7][o];
          atomicAdd(&agg[edst[es]*64 + o], v);
        }
        __syncthreads();
        s = 0;
      }
    }
  }
  if(s > 0){
    __syncthreads();
    for(int es=kc; es<s; es+=8){
      float v = red[es][0][o]+red[es][1][o]+red[es][2][o]+red[es][3][o]
              + red[es][4][o]+red[es][5][o]+red[es][6][o]+red[es][7][o];
      atomicAdd(&agg[edst[es]*64 + o], v);
    }
  }
}

// ---------------- node update v4: 8 nodes/block, 2 nodes/thread, bounded unroll ----------------
// thread (o = tid&63, g = tid>>6 in 0..3): channel o, nodes g*2, g*2+1
// __launch_bounds__(256,4) caps VGPR at 128; live set ~96 floats -> no spill by construction.
__global__ __launch_bounds__(256, 4) void k_node(const float* __restrict__ agg, const float* __restrict__ deg,
                                              float* __restrict__ outF, float* __restrict__ hF,
                                              const float* __restrict__ rootT, const float* __restrict__ convb,
                                              const float* __restrict__ wih, const float* __restrict__ whh,
                                              const float* __restrict__ bih, const float* __restrict__ bhh){
  int o = threadIdx.x & 63, g = threadIdx.x >> 6;
  int nb = blockIdx.x * 8;
  __shared__ __align__(16) float outs[8][64], hs[8][64], ms[8][64];

  for(int i=threadIdx.x; i<8*16; i+=256){
    ((float4*)outs)[i] = ((const float4*)(outF + (size_t)nb*64))[i];
    ((float4*)hs)[i]   = ((const float4*)(hF   + (size_t)nb*64))[i];
  }
  __syncthreads();

  // Phase A: m = lrelu(agg/deg + out @ root_w + conv_b) for 2 nodes
  float acc[2];
  float cb = convb[o];
  #pragma unroll
  for(int i=0;i<2;i++){
    int node = nb + g*2 + i;
    acc[i] = agg[(size_t)node*64 + o] / fmaxf(deg[node], 1.0f) + cb;
  }
  {
    const float4* rp = (const float4*)(rootT + o*64);
    #pragma unroll 4
    for(int c=0;c<16;c++){
      float4 w = rp[c];
      #pragma unroll
      for(int i=0;i<2;i++){
        float4 v = *(const float4*)&outs[g*2+i][c*4];
        acc[i] += v.x*w.x + v.y*w.y + v.z*w.z + v.w*w.w;
      }
    }
  }
  #pragma unroll
  for(int i=0;i<2;i++) ms[g*2+i][o] = lrelu(acc[i]);
  __syncthreads();

  // Phase B: GRU gates for 2 nodes (12 accumulators)
  float ir[2], iz[2], in_[2], hr[2], hz[2], hn[2];
  {
    float b0=bih[o], b1=bih[64+o], b2=bih[128+o];
    float c0=bhh[o], c1=bhh[64+o], c2=bhh[128+o];
    #pragma unroll
    for(int i=0;i<2;i++){ ir[i]=b0; iz[i]=b1; in_[i]=b2; hr[i]=c0; hz[i]=c1; hn[i]=c2; }
  }
  {
    const float4* w0 = (const float4*)(wih + (size_t)o*64);
    const float4* w1 = (const float4*)(wih + (size_t)(64+o)*64);
    const float4* w2 = (const float4*)(wih + (size_t)(128+o)*64);
    const float4* u0 = (const float4*)(whh + (size_t)o*64);
    const float4* u1 = (const float4*)(whh + (size_t)(64+o)*64);
    const float4* u2 = (const float4*)(whh + (size_t)(128+o)*64);
    #pragma unroll 2
    for(int c=0;c<16;c++){
      float4 a0=w0[c], a1v=w1[c], a2=w2[c], d0=u0[c], d1=u1[c], d2=u2[c];
      #pragma unroll
      for(int i=0;i<2;i++){
        float4 m4 = *(const float4*)&ms[g*2+i][c*4];
        float4 h4 = *(const float4*)&hs[g*2+i][c*4];
        ir[i]  += m4.x*a0.x + m4.y*a0.y + m4.z*a0.z + m4.w*a0.w;
        iz[i]  += m4.x*a1v.x+ m4.y*a1v.y+ m4.z*a1v.z+ m4.w*a1v.w;
        in_[i] += m4.x*a2.x + m4.y*a2.y + m4.z*a2.z + m4.w*a2.w;
        hr[i]  += h4.x*d0.x + h4.y*d0.y + h4.z*d0.z + h4.w*d0.w;
        hz[i]  += h4.x*d1.x + h4.y*d1.y + h4.z*d1.z + h4.w*d1.w;
        hn[i]  += h4.x*d2.x + h4.y*d2.y + h4.z*d2.z + h4.w*d2.w;
      }
    }
  }
  #pragma unroll
  for(int i=0;i<2;i++){
    int node = nb + g*2 + i;
    float r  = sigmoidf(ir[i] + hr[i]);
    float z  = sigmoidf(iz[i] + hz[i]);
    float ng = tanhf(in_[i] + r*hn[i]);
    float hnew = (1.f - z)*ng + z*hs[g*2+i][o];
    if(node < N_NODES){
      hF[(size_t)node*64 + o]   = hnew;
      outF[(size_t)node*64 + o] = hnew;
    }
  }
}

// ---------------- stem head ----------------
__global__ __launch_bounds__(128) void k_stem(const float* __restrict__ outF, const int* __restrict__ sidx,
                                              const float* __restrict__ s1w, const float* __restrict__ s1b,
                                              const float* __restrict__ s2w, const float* __restrict__ s2b,
                                              void* __restrict__ dout, const int* __restrict__ flag){
  int s = blockIdx.x, t = threadIdx.x;
  int isf = *flag;
  __shared__ __align__(16) float xs[64], hid[64];
  int a = sidx[s];
  if(t<64) xs[t] = outF[a*64+t];
  __syncthreads();
  if(t<64) hid[t] = lrelu(s1b[t] + dot64_f(s1w + t*64, (const float4*)xs));
  __syncthreads();
  if(t<105){
    float acc = s2b[t] + dot64_f(s2w + t*64, (const float4*)hid);
    store_out(dout, isf, OUT_STEM + s*105 + t, acc);
  }
}

// ---------------- jbond head ----------------
__global__ __launch_bounds__(128) void k_jbond(const float* __restrict__ outF, const int* __restrict__ jidx,
                                               const float* __restrict__ j1w, const float* __restrict__ j1b,
                                               const float* __restrict__ j2w, const float* __restrict__ j2b,
                                               void* __restrict__ dout, const int* __restrict__ flag){
  int jb = blockIdx.x, t = threadIdx.x;
  int isf = *flag;
  __shared__ __align__(16) float xs[2][64], hid[2][64];
  int at = t>>6, k = t&63;
  int a = jidx[jb*2 + at];
  xs[at][k] = outF[a*64+k];
  __syncthreads();
  hid[at][k] = lrelu(j1b[k] + dot64_f(j1w + k*64, (const float4*)xs[at]));
  __syncthreads();
  if(t<64){
    float p = (hid[0][t] + hid[1][t]) * j2w[t];
    #pragma unroll
    for(int s=32;s;s>>=1) p += __shfl_xor(p, s, 64);
    if(t==0) store_out(dout, isf, OUT_JB + jb, 0.5f*p + j2b[0]);
  }
}

// ---------------- Set2Set + final linear ----------------
__global__ __launch_bounds__(64) void k_s2s(const float* __restrict__ outF, const int* __restrict__ batch,
                                            const float* __restrict__ bih, const float* __restrict__ bhh,
                                            const float* __restrict__ loutw, const float* __restrict__ loutb,
                                            void* __restrict__ dout, const int* __restrict__ flag){
  int b = blockIdx.x, t = threadIdx.x;
  int isf = *flag;
  float i_ = bih[t]     + bhh[t];
  float g_ = bih[128+t] + bhh[128+t];
  float o_ = bih[192+t] + bhh[192+t];
  float c  = sigmoidf(i_)*tanhf(g_);
  float q  = sigmoidf(o_)*tanhf(c);

  int lo = lower_bound_i(batch, N_NODES, b);
  int hi = lower_bound_i(batch, N_NODES, b+1);

  float emax = -3.4e38f;
  for(int n=lo;n<hi;n++){
    float p = outF[n*64+t]*q;
    #pragma unroll
    for(int s=32;s;s>>=1) p += __shfl_xor(p, s, 64);
    emax = fmaxf(emax, p);
  }
  float Z = 0.f, racc = 0.f;
  for(int n=lo;n<hi;n++){
    float v = outF[n*64+t];
    float p = v*q;
    #pragma unroll
    for(int s=32;s;s>>=1) p += __shfl_xor(p, s, 64);
    float w = expf(p - emax);
    Z += w; racc += w*v;
  }
  float rp = (hi>lo) ? racc/Z : 0.f;

  #pragma unroll
  for(int j=0;j<2;j++){
    float p = q*loutw[j*128+t] + rp*loutw[j*128+64+t];
    #pragma unroll
    for(int s=32;s;s>>=1) p += __shfl_xor(p, s, 64);
    if(t==0) store_out(dout, isf, OUT_FINAL + b*2 + j, p + loutb[j]);
  }
}

extern "C" void kernel_launch(void* const* d_in, const int* in_sizes, int n_in,
                              void* d_out, int out_size, void* d_ws, size_t ws_size,
                              hipStream_t stream) {
  const int* edge_index  = (const int*)d_in[28];
  const int* stem_atmidx = (const int*)d_in[29];
  const int* jbond_atmidx= (const int*)d_in[30];
  const int* batch       = (const int*)d_in[31];

  char* ws = (char*)d_ws;
  size_t off = 0;
  auto alloc = [&](size_t bytes)->void*{ void* p = ws + off; off = (off + bytes + 255) & ~(size_t)255; return p; };

  int*   flag = (int*)  alloc(4);
  float* outF = (float*)alloc((size_t)PADN*64*4);
  float* hF   = (float*)alloc((size_t)PADN*64*4);
  float* agg  = (float*)alloc((size_t)PADN*64*4);
  float* a1   = (float*)alloc((size_t)N_EDGES*KP*4);
  float* W2f  = (float*)alloc((size_t)64*KP*64*4);
  float* deg  = (float*)alloc((size_t)PADN*4);
  int*   cnt  = (int*)  alloc((size_t)N_NODES*4);
  int*   offs = (int*)  alloc((size_t)(N_NODES+1)*4);
  int*   pos  = (int*)  alloc((size_t)N_NODES*4);
  int*   eidx = (int*)  alloc((size_t)N_EDGES*4);
  float* rootT= (float*)alloc(4096*4);

  static const int cvt_idx[N_CVT] = {0,1,2,3,4,5,6,7,8,9,10,11,12,13,14,15,16,17,18,19,20,21,24,25,26,27};
  CvtArgs A;
  float* cF[N_CVT];
  for(int i=0;i<N_CVT;i++){
    int src = cvt_idx[i];
    int n = in_sizes[src];
    cF[i] = (float*)alloc((size_t)n*4);
    A.src[i] = d_in[src];
    A.dst[i] = cF[i];
    A.n[i]   = n;
  }
  (void)ws_size; (void)n_in; (void)out_size;
  float* xF=cF[0];   float* eaF=cF[1];  float* l0w=cF[2];  float* l0b=cF[3];
  float* e1w=cF[4];  float* e1b=cF[5];  float* e2w=cF[6];  float* e2b=cF[7];
  float* rootw=cF[8];float* convb=cF[9];
  float* wih=cF[10]; float* whh=cF[11]; float* bih=cF[12]; float* bhh=cF[13];
  float* s1w=cF[14]; float* s1b=cF[15]; float* s2w=cF[16]; float* s2b=cF[17];
  float* j1w=cF[18]; float* j1b=cF[19]; float* j2w=cF[20]; float* j2b=cF[21];
  float* lbih=cF[22];float* lbhh=cF[23];float* loutw=cF[24];float* loutb=cF[25];

  hipMemsetAsync(flag, 0, 4, stream);
  hipMemsetAsync(deg,  0, (size_t)PADN*4, stream);
  hipMemsetAsync(cnt,  0, (size_t)N_NODES*4, stream);
  hipMemsetAsync(outF + (size_t)N_NODES*64, 0, (size_t)(PADN-N_NODES)*64*4, stream);
  hipMemsetAsync(hF   + (size_t)N_NODES*64, 0, (size_t)(PADN-N_NODES)*64*4, stream);

  k_sniff <<<128, 256, 0, stream>>>((const u16*)d_in[0], in_sizes[0], flag);
  k_cvt   <<<512, 256, 0, stream>>>(A, flag);

  k_lin0  <<<N_NODES, 64, 0, stream>>>(xF, l0w, l0b, outF, hF);
  k_a1    <<<N_EDGES, 128, 0, stream>>>(eaF, e1w, e1b, a1);
  k_packW2<<<(64*KP*64+255)/256, 256, 0, stream>>>(e2w, e2b, W2f);
  k_rootT <<<16, 256, 0, stream>>>(rootw, rootT);
  k_degcnt<<<(N_EDGES+255)/256, 256, 0, stream>>>(edge_index, deg, cnt);
  k_scan  <<<1, 1024, 0, stream>>>(cnt, offs, pos);
  k_fill  <<<(N_EDGES+255)/256, 256, 0, stream>>>(edge_index, pos, eidx);

  for(int it=0; it<6; it++){
    hipMemsetAsync(agg, 0, (size_t)PADN*64*4, stream);
    k_fused<<<N_NODES/8, 512, 0, stream>>>(outF, a1, W2f, edge_index + N_EDGES, offs, eidx, agg);
    k_node <<<PADN/8, 256, 0, stream>>>(agg, deg, outF, hF, rootT, convb, wih, whh, bih, bhh);
  }

  k_stem <<<N_STEMS, 128, 0, stream>>>(outF, stem_atmidx, s1w, s1b, s2w, s2b, d_out, flag);
  k_jbond<<<N_JBONDS, 128, 0, stream>>>(outF, jbond_atmidx, j1w, j1b, j2w, j2b, d_out, flag);
  k_s2s  <<<NUM_GRAPHS, 64, 0, stream>>>(outF, batch, lbih, lbhh, loutw, loutb, d_out, flag);
}

// Round 7
// 2620.520 us; speedup vs baseline: 1.8124x; 1.1643x over previous
//
#include <hip/hip_runtime.h>

typedef unsigned short u16;
typedef unsigned int   u32;

#define N_NODES    15000
#define PADN       15008          // multiple of 4, 8, 16
#define N_EDGES    30000
#define NUM_GRAPHS 600
#define N_STEMS    6000
#define N_JBONDS   3000

// d_out flat layout: [0,1200) final, [1200,631200) stem_preds, [631200,634200) jbond
#define OUT_FINAL  0
#define OUT_STEM   1200
#define OUT_JB     631200

// K-extent of folded a1/M tensors: 64 real + 1 bias column + 7 zero pad = 72
#define KP 72
#define N_CVT 26
#define ECH 16                    // edge-partial chunk in k_fused

__device__ __forceinline__ float u2f(u16 v){ union{u32 i; float f;} c; c.i=((u32)v)<<16; return c.f; }
__device__ __forceinline__ u16  f2b(float f){ union{float f; u32 u;} c; c.f=f; u32 u=c.u;
                                              return (u16)((u + 0x7fffu + ((u>>16)&1u))>>16); }
__device__ __forceinline__ float lrelu(float x){ return x>0.f ? x : 0.01f*x; }
__device__ __forceinline__ float sigmoidf(float x){ return 1.f/(1.f+expf(-x)); }

__device__ __forceinline__ float dot64_f(const float* __restrict__ w, const float4* __restrict__ x4){
  const float4* wp = (const float4*)w;
  float acc = 0.f;
  #pragma unroll
  for(int c=0;c<16;c++){ float4 a=wp[c], b=x4[c]; acc += a.x*b.x+a.y*b.y+a.z*b.z+a.w*b.w; }
  return acc;
}

__device__ __forceinline__ int lower_bound_i(const int* __restrict__ a, int n, int v){
  int lo=0, hi=n;
  while(lo<hi){ int m=(lo+hi)>>1; if(a[m]<v) lo=m+1; else hi=m; }
  return lo;
}

__device__ __forceinline__ void store_out(void* dout, int isf, int idx, float v){
  if(isf) ((float*)dout)[idx] = v;
  else    ((u16*)dout)[idx]   = f2b(v);
}

// ---------------- dtype sniff ----------------
__global__ __launch_bounds__(256) void k_sniff(const u16* __restrict__ x, int n, int* __restrict__ flag){
  int i = blockIdx.x*256 + threadIdx.x;
  int local = 0;
  for(; i < n; i += gridDim.x*256){
    u16 v = x[i];
    if(((v>>7)&0xFFu) == 0xFFu) local = 1;
  }
  if(local) atomicOr(flag, 1);
}

// ---------------- convert float inputs to f32 ----------------
struct CvtArgs { const void* src[N_CVT]; float* dst[N_CVT]; int n[N_CVT]; };

__global__ __launch_bounds__(256) void k_cvt(CvtArgs A, const int* __restrict__ flag){
  int isf = *flag;
  int tid = blockIdx.x*256 + threadIdx.x;
  int stride = gridDim.x*256;
  for(int b=0; b<N_CVT; b++){
    int n = A.n[b];
    const float* sf = (const float*)A.src[b];
    const u16*   sb = (const u16*)A.src[b];
    float* d = A.dst[b];
    for(int i=tid; i<n; i+=stride) d[i] = isf ? sf[i] : u2f(sb[i]);
  }
}

// ---------------- lin0 ----------------
__global__ __launch_bounds__(64) void k_lin0(const float* __restrict__ x, const float* __restrict__ w,
                                             const float* __restrict__ b,
                                             float* __restrict__ outF, float* __restrict__ hF){
  int n = blockIdx.x, o = threadIdx.x;
  __shared__ float xs[14];
  if(o<14) xs[o] = x[n*14+o];
  __syncthreads();
  float acc = b[o];
  #pragma unroll
  for(int i=0;i<14;i++) acc += xs[i]*w[o*14+i];
  acc = lrelu(acc);
  outF[n*64+o] = acc;
  hF[n*64+o]   = acc;
}

// ---------------- a1~[e][KP] ----------------
__global__ __launch_bounds__(128) void k_a1(const float* __restrict__ ea,
                                            const float* __restrict__ en1w, const float* __restrict__ en1b,
                                            float* __restrict__ a1){
  int e = blockIdx.x, k = threadIdx.x;
  if(k >= KP) return;
  float v;
  if(k < 64){
    float acc = en1b[k];
    #pragma unroll
    for(int c=0;c<4;c++) acc += ea[e*4+c] * en1w[k*4+c];
    v = lrelu(acc);
  } else v = (k==64) ? 1.0f : 0.0f;
  a1[(size_t)e*KP + k] = v;
}

// ---------------- W2f[j][k][o] ----------------
__global__ __launch_bounds__(256) void k_packW2(const float* __restrict__ en2w, const float* __restrict__ en2b,
                                                float* __restrict__ W2f){
  int idx = blockIdx.x*256 + threadIdx.x;
  if(idx >= 64*KP*64) return;
  int o = idx & 63;
  int r2 = idx >> 6;
  int k = r2 % KP;
  int j = r2 / KP;
  float v = 0.f;
  if(k < 64)       v = en2w[((size_t)(j*64+o))*64 + k];
  else if(k == 64) v = en2b[j*64+o];
  W2f[idx] = v;
}

// ---------------- rootT[o][j] = root_w[j][o] ----------------
__global__ __launch_bounds__(256) void k_rootT(const float* __restrict__ root, float* __restrict__ rootT){
  int i = blockIdx.x*256 + threadIdx.x;
  if(i < 4096){ int r=i>>6, c=i&63; rootT[c*64+r] = root[i]; }
}

// ---------------- deg/cnt ----------------
__global__ __launch_bounds__(256) void k_degcnt(const int* __restrict__ ei,
                                                float* __restrict__ deg, int* __restrict__ cnt){
  int e = blockIdx.x*256 + threadIdx.x;
  if(e < N_EDGES){
    atomicAdd(&deg[ei[N_EDGES + e]], 1.0f);
    atomicAdd(&cnt[ei[e]], 1);
  }
}

// ---------------- scan ----------------
__global__ __launch_bounds__(1024) void k_scan(const int* __restrict__ cnt,
                                               int* __restrict__ offs, int* __restrict__ pos){
  __shared__ int s[1024];
  int t = threadIdx.x;
  int base = t*15;
  int c[15];
  int loc = 0;
  #pragma unroll
  for(int i=0;i<15;i++){ int idx=base+i; int v=(idx<N_NODES)?cnt[idx]:0; c[i]=v; loc+=v; }
  s[t]=loc; __syncthreads();
  for(int d=1; d<1024; d<<=1){
    int v2 = (t>=d)? s[t-d] : 0;
    __syncthreads();
    s[t] += v2;
    __syncthreads();
  }
  int run = s[t]-loc;
  #pragma unroll
  for(int i=0;i<15;i++){
    int idx=base+i;
    if(idx<N_NODES){ offs[idx]=run; pos[idx]=run; }
    run += c[i];
  }
  if(t==1023) offs[N_NODES]=s[1023];
}

// ---------------- CSR fill ----------------
__global__ __launch_bounds__(256) void k_fill(const int* __restrict__ ei,
                                              int* __restrict__ pos, int* __restrict__ eidx){
  int e = blockIdx.x*256 + threadIdx.x;
  if(e < N_EDGES){
    int slot = atomicAdd(&pos[ei[e]], 1);
    eidx[slot] = e;
  }
}

// ---------------- fused M-build + message scatter (unchanged this round) ----------------
__global__ __launch_bounds__(512) void k_fused(const float* __restrict__ outF, const float* __restrict__ a1,
                                               const float* __restrict__ W2f,
                                               const int* __restrict__ ei_dst,
                                               const int* __restrict__ offs, const int* __restrict__ eidx,
                                               float* __restrict__ agg){
  int kc = threadIdx.x >> 6, o = threadIdx.x & 63;
  int nb = blockIdx.x * 8;
  __shared__ float outs[8][64];
  __shared__ float red[ECH][8][64];
  __shared__ int   edst[ECH];
  outs[kc][o] = outF[(nb+kc)*64 + o];
  __syncthreads();

  float Macc[8][9];
  #pragma unroll
  for(int n=0;n<8;n++)
    #pragma unroll
    for(int i=0;i<9;i++) Macc[n][i] = 0.f;

  for(int j=0;j<64;j++){
    const float* wr = W2f + ((size_t)j*KP + kc*9)*64 + o;
    float wv[9];
    #pragma unroll
    for(int i=0;i<9;i++) wv[i] = wr[i*64];
    #pragma unroll
    for(int n=0;n<8;n++){
      float oj = outs[n][j];
      #pragma unroll
      for(int i=0;i<9;i++) Macc[n][i] += oj * wv[i];
    }
  }

  int s = 0;
  #pragma unroll
  for(int n=0;n<8;n++){
    int node = nb + n;
    int lo = offs[node], hi = offs[node+1];
    for(int t=lo; t<hi; t++){
      int e = eidx[t];
      int dst = ei_dst[e];
      const float* ap = a1 + (size_t)e*KP + kc*9;
      float p = 0.f;
      #pragma unroll
      for(int i=0;i<9;i++) p += ap[i] * Macc[n][i];
      red[s][kc][o] = p;
      if(threadIdx.x == 0) edst[s] = dst;
      s++;
      if(s == ECH){
        __syncthreads();
        for(int es=kc; es<s; es+=8){
          float v = red[es][0][o]+red[es][1][o]+red[es][2][o]+red[es][3][o]
                  + red[es][4][o]+red[es][5][o]+red[es][6][o]+red[es][7][o];
          atomicAdd(&agg[edst[es]*64 + o], v);
        }
        __syncthreads();
        s = 0;
      }
    }
  }
  if(s > 0){
    __syncthreads();
    for(int es=kc; es<s; es+=8){
      float v = red[es][0][o]+red[es][1][o]+red[es][2][o]+red[es][3][o]
              + red[es][4][o]+red[es][5][o]+red[es][6][o]+red[es][7][o];
      atomicAdd(&agg[edst[es]*64 + o], v);
    }
  }
}

// ---------------- node update v5: round-3 proven codegen, 4 nodes/block ----------------
// thread (o = tid&63, g = tid>>6): channel o of node nb+g. 1 node per thread-group,
// 6 gate accumulators — identical inner code to round 3 (148 VGPR, zero spill).
// __launch_bounds__(256,2): VGPR cap 256, no forced-occupancy spill.
__global__ __launch_bounds__(256, 2) void k_node(const float* __restrict__ agg, const float* __restrict__ deg,
                                              float* __restrict__ outF, float* __restrict__ hF,
                                              const float* __restrict__ rootT, const float* __restrict__ convb,
                                              const float* __restrict__ wih, const float* __restrict__ whh,
                                              const float* __restrict__ bih, const float* __restrict__ bhh){
  int o = threadIdx.x & 63, g = threadIdx.x >> 6;
  int n = blockIdx.x * 4 + g;
  __shared__ __align__(16) float outs[4][64], ms[4][64], hs[4][64];
  outs[g][o] = outF[(size_t)n*64+o];
  hs[g][o]   = hF[(size_t)n*64+o];
  __syncthreads();
  float acc = agg[(size_t)n*64+o] / fmaxf(deg[n], 1.0f) + convb[o];
  {
    const float4* rp = (const float4*)(rootT + o*64);
    const float4* op = (const float4*)outs[g];
    #pragma unroll
    for(int c=0;c<16;c++){ float4 w=rp[c], v=op[c]; acc += v.x*w.x+v.y*w.y+v.z*w.z+v.w*w.w; }
  }
  ms[g][o] = lrelu(acc);
  __syncthreads();
  float ir = bih[o], iz = bih[64+o], in_ = bih[128+o];
  float hr = bhh[o], hz = bhh[64+o], hn  = bhh[128+o];
  {
    const float4* mp = (const float4*)ms[g];
    const float4* hp = (const float4*)hs[g];
    const float4* w0 = (const float4*)(wih + (size_t)o*64);
    const float4* w1 = (const float4*)(wih + (size_t)(64+o)*64);
    const float4* w2 = (const float4*)(wih + (size_t)(128+o)*64);
    const float4* u0 = (const float4*)(whh + (size_t)o*64);
    const float4* u1 = (const float4*)(whh + (size_t)(64+o)*64);
    const float4* u2 = (const float4*)(whh + (size_t)(128+o)*64);
    #pragma unroll
    for(int c=0;c<16;c++){
      float4 m4 = mp[c], h4 = hp[c];
      float4 a;
      a = w0[c]; ir  += m4.x*a.x+m4.y*a.y+m4.z*a.z+m4.w*a.w;
      a = w1[c]; iz  += m4.x*a.x+m4.y*a.y+m4.z*a.z+m4.w*a.w;
      a = w2[c]; in_ += m4.x*a.x+m4.y*a.y+m4.z*a.z+m4.w*a.w;
      a = u0[c]; hr  += h4.x*a.x+h4.y*a.y+h4.z*a.z+h4.w*a.w;
      a = u1[c]; hz  += h4.x*a.x+h4.y*a.y+h4.z*a.z+h4.w*a.w;
      a = u2[c]; hn  += h4.x*a.x+h4.y*a.y+h4.z*a.z+h4.w*a.w;
    }
  }
  float r  = sigmoidf(ir+hr);
  float z  = sigmoidf(iz+hz);
  float ng = tanhf(in_ + r*hn);
  float hnew = (1.f - z)*ng + z*hs[g][o];
  if(n < N_NODES){
    hF[(size_t)n*64+o]   = hnew;
    outF[(size_t)n*64+o] = hnew;
  }
}

// ---------------- stem head ----------------
__global__ __launch_bounds__(128) void k_stem(const float* __restrict__ outF, const int* __restrict__ sidx,
                                              const float* __restrict__ s1w, const float* __restrict__ s1b,
                                              const float* __restrict__ s2w, const float* __restrict__ s2b,
                                              void* __restrict__ dout, const int* __restrict__ flag){
  int s = blockIdx.x, t = threadIdx.x;
  int isf = *flag;
  __shared__ __align__(16) float xs[64], hid[64];
  int a = sidx[s];
  if(t<64) xs[t] = outF[a*64+t];
  __syncthreads();
  if(t<64) hid[t] = lrelu(s1b[t] + dot64_f(s1w + t*64, (const float4*)xs));
  __syncthreads();
  if(t<105){
    float acc = s2b[t] + dot64_f(s2w + t*64, (const float4*)hid);
    store_out(dout, isf, OUT_STEM + s*105 + t, acc);
  }
}

// ---------------- jbond head ----------------
__global__ __launch_bounds__(128) void k_jbond(const float* __restrict__ outF, const int* __restrict__ jidx,
                                               const float* __restrict__ j1w, const float* __restrict__ j1b,
                                               const float* __restrict__ j2w, const float* __restrict__ j2b,
                                               void* __restrict__ dout, const int* __restrict__ flag){
  int jb = blockIdx.x, t = threadIdx.x;
  int isf = *flag;
  __shared__ __align__(16) float xs[2][64], hid[2][64];
  int at = t>>6, k = t&63;
  int a = jidx[jb*2 + at];
  xs[at][k] = outF[a*64+k];
  __syncthreads();
  hid[at][k] = lrelu(j1b[k] + dot64_f(j1w + k*64, (const float4*)xs[at]));
  __syncthreads();
  if(t<64){
    float p = (hid[0][t] + hid[1][t]) * j2w[t];
    #pragma unroll
    for(int s=32;s;s>>=1) p += __shfl_xor(p, s, 64);
    if(t==0) store_out(dout, isf, OUT_JB + jb, 0.5f*p + j2b[0]);
  }
}

// ---------------- Set2Set + final linear ----------------
__global__ __launch_bounds__(64) void k_s2s(const float* __restrict__ outF, const int* __restrict__ batch,
                                            const float* __restrict__ bih, const float* __restrict__ bhh,
                                            const float* __restrict__ loutw, const float* __restrict__ loutb,
                                            void* __restrict__ dout, const int* __restrict__ flag){
  int b = blockIdx.x, t = threadIdx.x;
  int isf = *flag;
  float i_ = bih[t]     + bhh[t];
  float g_ = bih[128+t] + bhh[128+t];
  float o_ = bih[192+t] + bhh[192+t];
  float c  = sigmoidf(i_)*tanhf(g_);
  float q  = sigmoidf(o_)*tanhf(c);

  int lo = lower_bound_i(batch, N_NODES, b);
  int hi = lower_bound_i(batch, N_NODES, b+1);

  float emax = -3.4e38f;
  for(int n=lo;n<hi;n++){
    float p = outF[n*64+t]*q;
    #pragma unroll
    for(int s=32;s;s>>=1) p += __shfl_xor(p, s, 64);
    emax = fmaxf(emax, p);
  }
  float Z = 0.f, racc = 0.f;
  for(int n=lo;n<hi;n++){
    float v = outF[n*64+t];
    float p = v*q;
    #pragma unroll
    for(int s=32;s;s>>=1) p += __shfl_xor(p, s, 64);
    float w = expf(p - emax);
    Z += w; racc += w*v;
  }
  float rp = (hi>lo) ? racc/Z : 0.f;

  #pragma unroll
  for(int j=0;j<2;j++){
    float p = q*loutw[j*128+t] + rp*loutw[j*128+64+t];
    #pragma unroll
    for(int s=32;s;s>>=1) p += __shfl_xor(p, s, 64);
    if(t==0) store_out(dout, isf, OUT_FINAL + b*2 + j, p + loutb[j]);
  }
}

extern "C" void kernel_launch(void* const* d_in, const int* in_sizes, int n_in,
                              void* d_out, int out_size, void* d_ws, size_t ws_size,
                              hipStream_t stream) {
  const int* edge_index  = (const int*)d_in[28];
  const int* stem_atmidx = (const int*)d_in[29];
  const int* jbond_atmidx= (const int*)d_in[30];
  const int* batch       = (const int*)d_in[31];

  char* ws = (char*)d_ws;
  size_t off = 0;
  auto alloc = [&](size_t bytes)->void*{ void* p = ws + off; off = (off + bytes + 255) & ~(size_t)255; return p; };

  int*   flag = (int*)  alloc(4);
  float* outF = (float*)alloc((size_t)PADN*64*4);
  float* hF   = (float*)alloc((size_t)PADN*64*4);
  float* agg  = (float*)alloc((size_t)PADN*64*4);
  float* a1   = (float*)alloc((size_t)N_EDGES*KP*4);
  float* W2f  = (float*)alloc((size_t)64*KP*64*4);
  float* deg  = (float*)alloc((size_t)PADN*4);
  int*   cnt  = (int*)  alloc((size_t)N_NODES*4);
  int*   offs = (int*)  alloc((size_t)(N_NODES+1)*4);
  int*   pos  = (int*)  alloc((size_t)N_NODES*4);
  int*   eidx = (int*)  alloc((size_t)N_EDGES*4);
  float* rootT= (float*)alloc(4096*4);

  static const int cvt_idx[N_CVT] = {0,1,2,3,4,5,6,7,8,9,10,11,12,13,14,15,16,17,18,19,20,21,24,25,26,27};
  CvtArgs A;
  float* cF[N_CVT];
  for(int i=0;i<N_CVT;i++){
    int src = cvt_idx[i];
    int n = in_sizes[src];
    cF[i] = (float*)alloc((size_t)n*4);
    A.src[i] = d_in[src];
    A.dst[i] = cF[i];
    A.n[i]   = n;
  }
  (void)ws_size; (void)n_in; (void)out_size;
  float* xF=cF[0];   float* eaF=cF[1];  float* l0w=cF[2];  float* l0b=cF[3];
  float* e1w=cF[4];  float* e1b=cF[5];  float* e2w=cF[6];  float* e2b=cF[7];
  float* rootw=cF[8];float* convb=cF[9];
  float* wih=cF[10]; float* whh=cF[11]; float* bih=cF[12]; float* bhh=cF[13];
  float* s1w=cF[14]; float* s1b=cF[15]; float* s2w=cF[16]; float* s2b=cF[17];
  float* j1w=cF[18]; float* j1b=cF[19]; float* j2w=cF[20]; float* j2b=cF[21];
  float* lbih=cF[22];float* lbhh=cF[23];float* loutw=cF[24];float* loutb=cF[25];

  hipMemsetAsync(flag, 0, 4, stream);
  hipMemsetAsync(deg,  0, (size_t)PADN*4, stream);
  hipMemsetAsync(cnt,  0, (size_t)N_NODES*4, stream);
  hipMemsetAsync(outF + (size_t)N_NODES*64, 0, (size_t)(PADN-N_NODES)*64*4, stream);
  hipMemsetAsync(hF   + (size_t)N_NODES*64, 0, (size_t)(PADN-N_NODES)*64*4, stream);

  k_sniff <<<128, 256, 0, stream>>>((const u16*)d_in[0], in_sizes[0], flag);
  k_cvt   <<<512, 256, 0, stream>>>(A, flag);

  k_lin0  <<<N_NODES, 64, 0, stream>>>(xF, l0w, l0b, outF, hF);
  k_a1    <<<N_EDGES, 128, 0, stream>>>(eaF, e1w, e1b, a1);
  k_packW2<<<(64*KP*64+255)/256, 256, 0, stream>>>(e2w, e2b, W2f);
  k_rootT <<<16, 256, 0, stream>>>(rootw, rootT);
  k_degcnt<<<(N_EDGES+255)/256, 256, 0, stream>>>(edge_index, deg, cnt);
  k_scan  <<<1, 1024, 0, stream>>>(cnt, offs, pos);
  k_fill  <<<(N_EDGES+255)/256, 256, 0, stream>>>(edge_index, pos, eidx);

  for(int it=0; it<6; it++){
    hipMemsetAsync(agg, 0, (size_t)PADN*64*4, stream);
    k_fused<<<N_NODES/8, 512, 0, stream>>>(outF, a1, W2f, edge_index + N_EDGES, offs, eidx, agg);
    k_node <<<PADN/4, 256, 0, stream>>>(agg, deg, outF, hF, rootT, convb, wih, whh, bih, bhh);
  }

  k_stem <<<N_STEMS, 128, 0, stream>>>(outF, stem_atmidx, s1w, s1b, s2w, s2b, d_out, flag);
  k_jbond<<<N_JBONDS, 128, 0, stream>>>(outF, jbond_atmidx, j1w, j1b, j2w, j2b, d_out, flag);
  k_s2s  <<<NUM_GRAPHS, 64, 0, stream>>>(outF, batch, lbih, lbhh, loutw, loutb, d_out, flag);
}

// Round 8
// 1656.996 us; speedup vs baseline: 2.8663x; 1.5815x over previous
//
#include <hip/hip_runtime.h>

typedef unsigned short u16;
typedef unsigned int   u32;

#define N_NODES    15000
#define PADN       15008          // multiple of 4, 8, 16
#define N_EDGES    30000
#define NUM_GRAPHS 600
#define N_STEMS    6000
#define N_JBONDS   3000

// d_out flat layout: [0,1200) final, [1200,631200) stem_preds, [631200,634200) jbond
#define OUT_FINAL  0
#define OUT_STEM   1200
#define OUT_JB     631200

// K-extent of folded a1/M tensors: 64 real + 1 bias column + 7 zero pad = 72
#define KP 72
#define N_CVT 26
#define ECH 16                    // edge-partial chunk in k_fused

__device__ __forceinline__ float u2f(u16 v){ union{u32 i; float f;} c; c.i=((u32)v)<<16; return c.f; }
__device__ __forceinline__ u16  f2b(float f){ union{float f; u32 u;} c; c.f=f; u32 u=c.u;
                                              return (u16)((u + 0x7fffu + ((u>>16)&1u))>>16); }
__device__ __forceinline__ float lrelu(float x){ return x>0.f ? x : 0.01f*x; }
__device__ __forceinline__ float sigmoidf(float x){ return 1.f/(1.f+expf(-x)); }

__device__ __forceinline__ float dot64_f(const float* __restrict__ w, const float4* __restrict__ x4){
  const float4* wp = (const float4*)w;
  float acc = 0.f;
  #pragma unroll
  for(int c=0;c<16;c++){ float4 a=wp[c], b=x4[c]; acc += a.x*b.x+a.y*b.y+a.z*b.z+a.w*b.w; }
  return acc;
}

__device__ __forceinline__ int lower_bound_i(const int* __restrict__ a, int n, int v){
  int lo=0, hi=n;
  while(lo<hi){ int m=(lo+hi)>>1; if(a[m]<v) lo=m+1; else hi=m; }
  return lo;
}

__device__ __forceinline__ void store_out(void* dout, int isf, int idx, float v){
  if(isf) ((float*)dout)[idx] = v;
  else    ((u16*)dout)[idx]   = f2b(v);
}

// ---------------- dtype sniff ----------------
__global__ __launch_bounds__(256) void k_sniff(const u16* __restrict__ x, int n, int* __restrict__ flag){
  int i = blockIdx.x*256 + threadIdx.x;
  int local = 0;
  for(; i < n; i += gridDim.x*256){
    u16 v = x[i];
    if(((v>>7)&0xFFu) == 0xFFu) local = 1;
  }
  if(local) atomicOr(flag, 1);
}

// ---------------- convert float inputs to f32 ----------------
struct CvtArgs { const void* src[N_CVT]; float* dst[N_CVT]; int n[N_CVT]; };

__global__ __launch_bounds__(256) void k_cvt(CvtArgs A, const int* __restrict__ flag){
  int isf = *flag;
  int tid = blockIdx.x*256 + threadIdx.x;
  int stride = gridDim.x*256;
  for(int b=0; b<N_CVT; b++){
    int n = A.n[b];
    const float* sf = (const float*)A.src[b];
    const u16*   sb = (const u16*)A.src[b];
    float* d = A.dst[b];
    for(int i=tid; i<n; i+=stride) d[i] = isf ? sf[i] : u2f(sb[i]);
  }
}

// ---------------- lin0 (h == out invariant: single buffer) ----------------
__global__ __launch_bounds__(64) void k_lin0(const float* __restrict__ x, const float* __restrict__ w,
                                             const float* __restrict__ b,
                                             float* __restrict__ outF){
  int n = blockIdx.x, o = threadIdx.x;
  __shared__ float xs[14];
  if(o<14) xs[o] = x[n*14+o];
  __syncthreads();
  float acc = b[o];
  #pragma unroll
  for(int i=0;i<14;i++) acc += xs[i]*w[o*14+i];
  outF[n*64+o] = lrelu(acc);
}

// ---------------- a1~[e][KP] ----------------
__global__ __launch_bounds__(128) void k_a1(const float* __restrict__ ea,
                                            const float* __restrict__ en1w, const float* __restrict__ en1b,
                                            float* __restrict__ a1){
  int e = blockIdx.x, k = threadIdx.x;
  if(k >= KP) return;
  float v;
  if(k < 64){
    float acc = en1b[k];
    #pragma unroll
    for(int c=0;c<4;c++) acc += ea[e*4+c] * en1w[k*4+c];
    v = lrelu(acc);
  } else v = (k==64) ? 1.0f : 0.0f;
  a1[(size_t)e*KP + k] = v;
}

// ---------------- W2f[j][k][o] ----------------
__global__ __launch_bounds__(256) void k_packW2(const float* __restrict__ en2w, const float* __restrict__ en2b,
                                                float* __restrict__ W2f){
  int idx = blockIdx.x*256 + threadIdx.x;
  if(idx >= 64*KP*64) return;
  int o = idx & 63;
  int r2 = idx >> 6;
  int k = r2 % KP;
  int j = r2 / KP;
  float v = 0.f;
  if(k < 64)       v = en2w[((size_t)(j*64+o))*64 + k];
  else if(k == 64) v = en2b[j*64+o];
  W2f[idx] = v;
}

// ---------------- packed coalesced weights for k_node ----------------
// rootP[j4*64+o] = {root_w[4j4+k][o]}  (acc_o += sum_j root_w[j][o]*out[j])
__global__ __launch_bounds__(256) void k_packRoot(const float* __restrict__ root, float4* __restrict__ rootP){
  int idx = blockIdx.x*256 + threadIdx.x;
  if(idx >= 1024) return;
  int o = idx & 63, j4 = idx >> 6;
  float4 v;
  v.x = root[(4*j4+0)*64 + o];
  v.y = root[(4*j4+1)*64 + o];
  v.z = root[(4*j4+2)*64 + o];
  v.w = root[(4*j4+3)*64 + o];
  rootP[idx] = v;
}

// gateP[(g*16+j4)*64+o] = {w[(g*64+o)*64 + 4j4+k]}  for wih and whh
__global__ __launch_bounds__(256) void k_packGates(const float* __restrict__ wih, const float* __restrict__ whh,
                                                   float4* __restrict__ wihP, float4* __restrict__ whhP){
  int idx = blockIdx.x*256 + threadIdx.x;
  if(idx >= 3072) return;
  int o = idx & 63, j4 = (idx >> 6) & 15, g = idx >> 10;
  int row = (g*64 + o)*64 + 4*j4;
  float4 a, b;
  a.x = wih[row+0]; a.y = wih[row+1]; a.z = wih[row+2]; a.w = wih[row+3];
  b.x = whh[row+0]; b.y = whh[row+1]; b.z = whh[row+2]; b.w = whh[row+3];
  wihP[idx] = a; whhP[idx] = b;
}

// ---------------- deg/cnt ----------------
__global__ __launch_bounds__(256) void k_degcnt(const int* __restrict__ ei,
                                                float* __restrict__ deg, int* __restrict__ cnt){
  int e = blockIdx.x*256 + threadIdx.x;
  if(e < N_EDGES){
    atomicAdd(&deg[ei[N_EDGES + e]], 1.0f);
    atomicAdd(&cnt[ei[e]], 1);
  }
}

// ---------------- scan ----------------
__global__ __launch_bounds__(1024) void k_scan(const int* __restrict__ cnt,
                                               int* __restrict__ offs, int* __restrict__ pos){
  __shared__ int s[1024];
  int t = threadIdx.x;
  int base = t*15;
  int c[15];
  int loc = 0;
  #pragma unroll
  for(int i=0;i<15;i++){ int idx=base+i; int v=(idx<N_NODES)?cnt[idx]:0; c[i]=v; loc+=v; }
  s[t]=loc; __syncthreads();
  for(int d=1; d<1024; d<<=1){
    int v2 = (t>=d)? s[t-d] : 0;
    __syncthreads();
    s[t] += v2;
    __syncthreads();
  }
  int run = s[t]-loc;
  #pragma unroll
  for(int i=0;i<15;i++){
    int idx=base+i;
    if(idx<N_NODES){ offs[idx]=run; pos[idx]=run; }
    run += c[i];
  }
  if(t==1023) offs[N_NODES]=s[1023];
}

// ---------------- CSR fill ----------------
__global__ __launch_bounds__(256) void k_fill(const int* __restrict__ ei,
                                              int* __restrict__ pos, int* __restrict__ eidx){
  int e = blockIdx.x*256 + threadIdx.x;
  if(e < N_EDGES){
    int slot = atomicAdd(&pos[ei[e]], 1);
    eidx[slot] = e;
  }
}

// ---------------- fused M-build + message scatter (unchanged) ----------------
__global__ __launch_bounds__(512) void k_fused(const float* __restrict__ outF, const float* __restrict__ a1,
                                               const float* __restrict__ W2f,
                                               const int* __restrict__ ei_dst,
                                               const int* __restrict__ offs, const int* __restrict__ eidx,
                                               float* __restrict__ agg){
  int kc = threadIdx.x >> 6, o = threadIdx.x & 63;
  int nb = blockIdx.x * 8;
  __shared__ float outs[8][64];
  __shared__ float red[ECH][8][64];
  __shared__ int   edst[ECH];
  outs[kc][o] = outF[(nb+kc)*64 + o];
  __syncthreads();

  float Macc[8][9];
  #pragma unroll
  for(int n=0;n<8;n++)
    #pragma unroll
    for(int i=0;i<9;i++) Macc[n][i] = 0.f;

  for(int j=0;j<64;j++){
    const float* wr = W2f + ((size_t)j*KP + kc*9)*64 + o;
    float wv[9];
    #pragma unroll
    for(int i=0;i<9;i++) wv[i] = wr[i*64];
    #pragma unroll
    for(int n=0;n<8;n++){
      float oj = outs[n][j];
      #pragma unroll
      for(int i=0;i<9;i++) Macc[n][i] += oj * wv[i];
    }
  }

  int s = 0;
  #pragma unroll
  for(int n=0;n<8;n++){
    int node = nb + n;
    int lo = offs[node], hi = offs[node+1];
    for(int t=lo; t<hi; t++){
      int e = eidx[t];
      int dst = ei_dst[e];
      const float* ap = a1 + (size_t)e*KP + kc*9;
      float p = 0.f;
      #pragma unroll
      for(int i=0;i<9;i++) p += ap[i] * Macc[n][i];
      red[s][kc][o] = p;
      if(threadIdx.x == 0) edst[s] = dst;
      s++;
      if(s == ECH){
        __syncthreads();
        for(int es=kc; es<s; es+=8){
          float v = red[es][0][o]+red[es][1][o]+red[es][2][o]+red[es][3][o]
                  + red[es][4][o]+red[es][5][o]+red[es][6][o]+red[es][7][o];
          atomicAdd(&agg[edst[es]*64 + o], v);
        }
        __syncthreads();
        s = 0;
      }
    }
  }
  if(s > 0){
    __syncthreads();
    for(int es=kc; es<s; es+=8){
      float v = red[es][0][o]+red[es][1][o]+red[es][2][o]+red[es][3][o]
              + red[es][4][o]+red[es][5][o]+red[es][6][o]+red[es][7][o];
      atomicAdd(&agg[edst[es]*64 + o], v);
    }
  }
}

// ---------------- node update v6: coalesced packed weights, h==out single buffer ----------------
// thread (o = tid&63, g = tid>>6): channel o of node blockIdx*4+g.
// Weight load P[j4*64+o]: 64 lanes x 16B contiguous -> 4 cache lines/instr (vs 64 before).
__global__ __launch_bounds__(256, 2) void k_node(const float* __restrict__ agg, const float* __restrict__ deg,
                                              float* __restrict__ outF,
                                              const float4* __restrict__ rootP, const float* __restrict__ convb,
                                              const float4* __restrict__ wihP, const float4* __restrict__ whhP,
                                              const float* __restrict__ bih, const float* __restrict__ bhh){
  int o = threadIdx.x & 63, g = threadIdx.x >> 6;
  int n = blockIdx.x * 4 + g;
  __shared__ __align__(16) float outs[4][64], ms[4][64];
  outs[g][o] = outF[(size_t)n*64+o];
  __syncthreads();

  const float4* op = (const float4*)outs[g];
  float acc = agg[(size_t)n*64+o] / fmaxf(deg[n], 1.0f) + convb[o];
  #pragma unroll 8
  for(int j4=0;j4<16;j4++){
    float4 w = rootP[j4*64+o];       // coalesced
    float4 m = op[j4];               // LDS broadcast
    acc += w.x*m.x + w.y*m.y + w.z*m.z + w.w*m.w;
  }
  ms[g][o] = lrelu(acc);
  __syncthreads();

  float ir = bih[o], iz = bih[64+o], in_ = bih[128+o];
  float hr = bhh[o], hz = bhh[64+o], hn  = bhh[128+o];
  const float4* mp = (const float4*)ms[g];
  #pragma unroll 4
  for(int j4=0;j4<16;j4++){
    float4 m4 = mp[j4], h4 = op[j4];
    float4 a;
    a = wihP[(0*16+j4)*64+o]; ir  += m4.x*a.x+m4.y*a.y+m4.z*a.z+m4.w*a.w;
    a = wihP[(1*16+j4)*64+o]; iz  += m4.x*a.x+m4.y*a.y+m4.z*a.z+m4.w*a.w;
    a = wihP[(2*16+j4)*64+o]; in_ += m4.x*a.x+m4.y*a.y+m4.z*a.z+m4.w*a.w;
    a = whhP[(0*16+j4)*64+o]; hr  += h4.x*a.x+h4.y*a.y+h4.z*a.z+h4.w*a.w;
    a = whhP[(1*16+j4)*64+o]; hz  += h4.x*a.x+h4.y*a.y+h4.z*a.z+h4.w*a.w;
    a = whhP[(2*16+j4)*64+o]; hn  += h4.x*a.x+h4.y*a.y+h4.z*a.z+h4.w*a.w;
  }
  float r  = sigmoidf(ir+hr);
  float z  = sigmoidf(iz+hz);
  float ng = tanhf(in_ + r*hn);
  float hnew = (1.f - z)*ng + z*outs[g][o];
  if(n < N_NODES) outF[(size_t)n*64+o] = hnew;
}

// ---------------- stem head ----------------
__global__ __launch_bounds__(128) void k_stem(const float* __restrict__ outF, const int* __restrict__ sidx,
                                              const float* __restrict__ s1w, const float* __restrict__ s1b,
                                              const float* __restrict__ s2w, const float* __restrict__ s2b,
                                              void* __restrict__ dout, const int* __restrict__ flag){
  int s = blockIdx.x, t = threadIdx.x;
  int isf = *flag;
  __shared__ __align__(16) float xs[64], hid[64];
  int a = sidx[s];
  if(t<64) xs[t] = outF[a*64+t];
  __syncthreads();
  if(t<64) hid[t] = lrelu(s1b[t] + dot64_f(s1w + t*64, (const float4*)xs));
  __syncthreads();
  if(t<105){
    float acc = s2b[t] + dot64_f(s2w + t*64, (const float4*)hid);
    store_out(dout, isf, OUT_STEM + s*105 + t, acc);
  }
}

// ---------------- jbond head ----------------
__global__ __launch_bounds__(128) void k_jbond(const float* __restrict__ outF, const int* __restrict__ jidx,
                                               const float* __restrict__ j1w, const float* __restrict__ j1b,
                                               const float* __restrict__ j2w, const float* __restrict__ j2b,
                                               void* __restrict__ dout, const int* __restrict__ flag){
  int jb = blockIdx.x, t = threadIdx.x;
  int isf = *flag;
  __shared__ __align__(16) float xs[2][64], hid[2][64];
  int at = t>>6, k = t&63;
  int a = jidx[jb*2 + at];
  xs[at][k] = outF[a*64+k];
  __syncthreads();
  hid[at][k] = lrelu(j1b[k] + dot64_f(j1w + k*64, (const float4*)xs[at]));
  __syncthreads();
  if(t<64){
    float p = (hid[0][t] + hid[1][t]) * j2w[t];
    #pragma unroll
    for(int s=32;s;s>>=1) p += __shfl_xor(p, s, 64);
    if(t==0) store_out(dout, isf, OUT_JB + jb, 0.5f*p + j2b[0]);
  }
}

// ---------------- Set2Set + final linear ----------------
__global__ __launch_bounds__(64) void k_s2s(const float* __restrict__ outF, const int* __restrict__ batch,
                                            const float* __restrict__ bih, const float* __restrict__ bhh,
                                            const float* __restrict__ loutw, const float* __restrict__ loutb,
                                            void* __restrict__ dout, const int* __restrict__ flag){
  int b = blockIdx.x, t = threadIdx.x;
  int isf = *flag;
  float i_ = bih[t]     + bhh[t];
  float g_ = bih[128+t] + bhh[128+t];
  float o_ = bih[192+t] + bhh[192+t];
  float c  = sigmoidf(i_)*tanhf(g_);
  float q  = sigmoidf(o_)*tanhf(c);

  int lo = lower_bound_i(batch, N_NODES, b);
  int hi = lower_bound_i(batch, N_NODES, b+1);

  float emax = -3.4e38f;
  for(int n=lo;n<hi;n++){
    float p = outF[n*64+t]*q;
    #pragma unroll
    for(int s=32;s;s>>=1) p += __shfl_xor(p, s, 64);
    emax = fmaxf(emax, p);
  }
  float Z = 0.f, racc = 0.f;
  for(int n=lo;n<hi;n++){
    float v = outF[n*64+t];
    float p = v*q;
    #pragma unroll
    for(int s=32;s;s>>=1) p += __shfl_xor(p, s, 64);
    float w = expf(p - emax);
    Z += w; racc += w*v;
  }
  float rp = (hi>lo) ? racc/Z : 0.f;

  #pragma unroll
  for(int j=0;j<2;j++){
    float p = q*loutw[j*128+t] + rp*loutw[j*128+64+t];
    #pragma unroll
    for(int s=32;s;s>>=1) p += __shfl_xor(p, s, 64);
    if(t==0) store_out(dout, isf, OUT_FINAL + b*2 + j, p + loutb[j]);
  }
}

extern "C" void kernel_launch(void* const* d_in, const int* in_sizes, int n_in,
                              void* d_out, int out_size, void* d_ws, size_t ws_size,
                              hipStream_t stream) {
  const int* edge_index  = (const int*)d_in[28];
  const int* stem_atmidx = (const int*)d_in[29];
  const int* jbond_atmidx= (const int*)d_in[30];
  const int* batch       = (const int*)d_in[31];

  char* ws = (char*)d_ws;
  size_t off = 0;
  auto alloc = [&](size_t bytes)->void*{ void* p = ws + off; off = (off + bytes + 255) & ~(size_t)255; return p; };

  int*   flag = (int*)  alloc(4);
  float* outF = (float*)alloc((size_t)PADN*64*4);
  float* agg  = (float*)alloc((size_t)PADN*64*4);
  float* a1   = (float*)alloc((size_t)N_EDGES*KP*4);
  float* W2f  = (float*)alloc((size_t)64*KP*64*4);
  float* deg  = (float*)alloc((size_t)PADN*4);
  int*   cnt  = (int*)  alloc((size_t)N_NODES*4);
  int*   offs = (int*)  alloc((size_t)(N_NODES+1)*4);
  int*   pos  = (int*)  alloc((size_t)N_NODES*4);
  int*   eidx = (int*)  alloc((size_t)N_EDGES*4);
  float4* rootP = (float4*)alloc(1024*16);
  float4* wihP  = (float4*)alloc(3072*16);
  float4* whhP  = (float4*)alloc(3072*16);

  static const int cvt_idx[N_CVT] = {0,1,2,3,4,5,6,7,8,9,10,11,12,13,14,15,16,17,18,19,20,21,24,25,26,27};
  CvtArgs A;
  float* cF[N_CVT];
  for(int i=0;i<N_CVT;i++){
    int src = cvt_idx[i];
    int n = in_sizes[src];
    cF[i] = (float*)alloc((size_t)n*4);
    A.src[i] = d_in[src];
    A.dst[i] = cF[i];
    A.n[i]   = n;
  }
  (void)ws_size; (void)n_in; (void)out_size;
  float* xF=cF[0];   float* eaF=cF[1];  float* l0w=cF[2];  float* l0b=cF[3];
  float* e1w=cF[4];  float* e1b=cF[5];  float* e2w=cF[6];  float* e2b=cF[7];
  float* rootw=cF[8];float* convb=cF[9];
  float* wih=cF[10]; float* whh=cF[11]; float* bih=cF[12]; float* bhh=cF[13];
  float* s1w=cF[14]; float* s1b=cF[15]; float* s2w=cF[16]; float* s2b=cF[17];
  float* j1w=cF[18]; float* j1b=cF[19]; float* j2w=cF[20]; float* j2b=cF[21];
  float* lbih=cF[22];float* lbhh=cF[23];float* loutw=cF[24];float* loutb=cF[25];

  hipMemsetAsync(flag, 0, 4, stream);
  hipMemsetAsync(deg,  0, (size_t)PADN*4, stream);
  hipMemsetAsync(cnt,  0, (size_t)N_NODES*4, stream);
  hipMemsetAsync(outF + (size_t)N_NODES*64, 0, (size_t)(PADN-N_NODES)*64*4, stream);

  k_sniff <<<128, 256, 0, stream>>>((const u16*)d_in[0], in_sizes[0], flag);
  k_cvt   <<<512, 256, 0, stream>>>(A, flag);

  k_lin0    <<<N_NODES, 64, 0, stream>>>(xF, l0w, l0b, outF);
  k_a1      <<<N_EDGES, 128, 0, stream>>>(eaF, e1w, e1b, a1);
  k_packW2  <<<(64*KP*64+255)/256, 256, 0, stream>>>(e2w, e2b, W2f);
  k_packRoot<<<4, 256, 0, stream>>>(rootw, rootP);
  k_packGates<<<12, 256, 0, stream>>>(wih, whh, wihP, whhP);
  k_degcnt  <<<(N_EDGES+255)/256, 256, 0, stream>>>(edge_index, deg, cnt);
  k_scan    <<<1, 1024, 0, stream>>>(cnt, offs, pos);
  k_fill    <<<(N_EDGES+255)/256, 256, 0, stream>>>(edge_index, pos, eidx);

  for(int it=0; it<6; it++){
    hipMemsetAsync(agg, 0, (size_t)PADN*64*4, stream);
    k_fused<<<N_NODES/8, 512, 0, stream>>>(outF, a1, W2f, edge_index + N_EDGES, offs, eidx, agg);
    k_node <<<PADN/4, 256, 0, stream>>>(agg, deg, outF, rootP, convb, wihP, whhP, bih, bhh);
  }

  k_stem <<<N_STEMS, 128, 0, stream>>>(outF, stem_atmidx, s1w, s1b, s2w, s2b, d_out, flag);
  k_jbond<<<N_JBONDS, 128, 0, stream>>>(outF, jbond_atmidx, j1w, j1b, j2w, j2b, d_out, flag);
  k_s2s  <<<NUM_GRAPHS, 64, 0, stream>>>(outF, batch, lbih, lbhh, loutw, loutb, d_out, flag);
}

// Round 9
// 1272.625 us; speedup vs baseline: 3.7320x; 1.3020x over previous
//
#include <hip/hip_runtime.h>

typedef unsigned short u16;
typedef unsigned int   u32;

#define N_NODES    15000
#define PADN       15008
#define N_EDGES    30000
#define NUM_GRAPHS 600
#define N_STEMS    6000
#define N_JBONDS   3000

#define OUT_FINAL  0
#define OUT_STEM   1200
#define OUT_JB     631200

#define KP 72                 // a1 K-extent (64 + bias + pad)
#define SKK 68                // Ml per-(node,o) stride in bf16 (64 + bias + 3 pad)
#define NPRIME (64*SKK)       // 4352 GEMM N dimension
#define TILES ((NPRIME/8)/16) // 34 tiles of 16 cols per wave
#define N_CVT 26

typedef short frag8 __attribute__((ext_vector_type(8)));   // 8 bf16
typedef float facc4 __attribute__((ext_vector_type(4)));   // 4 f32 acc

__device__ __forceinline__ float u2f(u16 v){ union{u32 i; float f;} c; c.i=((u32)v)<<16; return c.f; }
__device__ __forceinline__ u16  f2b(float f){ union{float f; u32 u;} c; c.f=f; u32 u=c.u;
                                              return (u16)((u + 0x7fffu + ((u>>16)&1u))>>16); }
__device__ __forceinline__ float lrelu(float x){ return x>0.f ? x : 0.01f*x; }
__device__ __forceinline__ float sigmoidf(float x){ return 1.f/(1.f+expf(-x)); }

__device__ __forceinline__ float dot64_f(const float* __restrict__ w, const float4* __restrict__ x4){
  const float4* wp = (const float4*)w;
  float acc = 0.f;
  #pragma unroll
  for(int c=0;c<16;c++){ float4 a=wp[c], b=x4[c]; acc += a.x*b.x+a.y*b.y+a.z*b.z+a.w*b.w; }
  return acc;
}

__device__ __forceinline__ int lower_bound_i(const int* __restrict__ a, int n, int v){
  int lo=0, hi=n;
  while(lo<hi){ int m=(lo+hi)>>1; if(a[m]<v) lo=m+1; else hi=m; }
  return lo;
}

__device__ __forceinline__ void store_out(void* dout, int isf, int idx, float v){
  if(isf) ((float*)dout)[idx] = v;
  else    ((u16*)dout)[idx]   = f2b(v);
}

// ---------------- dtype sniff ----------------
__global__ __launch_bounds__(256) void k_sniff(const u16* __restrict__ x, int n, int* __restrict__ flag){
  int i = blockIdx.x*256 + threadIdx.x;
  int local = 0;
  for(; i < n; i += gridDim.x*256){
    u16 v = x[i];
    if(((v>>7)&0xFFu) == 0xFFu) local = 1;
  }
  if(local) atomicOr(flag, 1);
}

// ---------------- convert float inputs to f32 ----------------
struct CvtArgs { const void* src[N_CVT]; float* dst[N_CVT]; int n[N_CVT]; };

__global__ __launch_bounds__(256) void k_cvt(CvtArgs A, const int* __restrict__ flag){
  int isf = *flag;
  int tid = blockIdx.x*256 + threadIdx.x;
  int stride = gridDim.x*256;
  for(int b=0; b<N_CVT; b++){
    int n = A.n[b];
    const float* sf = (const float*)A.src[b];
    const u16*   sb = (const u16*)A.src[b];
    float* d = A.dst[b];
    for(int i=tid; i<n; i+=stride) d[i] = isf ? sf[i] : u2f(sb[i]);
  }
}

// ---------------- lin0 ----------------
__global__ __launch_bounds__(64) void k_lin0(const float* __restrict__ x, const float* __restrict__ w,
                                             const float* __restrict__ b,
                                             float* __restrict__ outF){
  int n = blockIdx.x, o = threadIdx.x;
  __shared__ float xs[14];
  if(o<14) xs[o] = x[n*14+o];
  __syncthreads();
  float acc = b[o];
  #pragma unroll
  for(int i=0;i<14;i++) acc += xs[i]*w[o*14+i];
  outF[n*64+o] = lrelu(acc);
}

// ---------------- a1~[e][KP] ----------------
__global__ __launch_bounds__(128) void k_a1(const float* __restrict__ ea,
                                            const float* __restrict__ en1w, const float* __restrict__ en1b,
                                            float* __restrict__ a1){
  int e = blockIdx.x, k = threadIdx.x;
  if(k >= KP) return;
  float v;
  if(k < 64){
    float acc = en1b[k];
    #pragma unroll
    for(int c=0;c<4;c++) acc += ea[e*4+c] * en1w[k*4+c];
    v = lrelu(acc);
  } else v = (k==64) ? 1.0f : 0.0f;
  a1[(size_t)e*KP + k] = v;
}

// ---------------- W2b: bf16 B-operand, fragment-ordered ----------------
// W2b[(Kc*NPRIME + n')*8 + j] = bf16(B[i=Kc*8+j][n']), n' = o*SKK + kk
// B[i][n'] = en2w[(i*64+o)*64+kk] (kk<64), en2b[i*64+o] (kk==64), 0 else
__global__ __launch_bounds__(256) void k_packW2b(const float* __restrict__ en2w, const float* __restrict__ en2b,
                                                 u16* __restrict__ W2b){
  int idx = blockIdx.x*256 + threadIdx.x;
  if(idx >= 8*NPRIME*8) return;
  int j  = idx & 7;
  int np = (idx >> 3) % NPRIME;
  int Kc = idx / (NPRIME*8);
  int i  = Kc*8 + j;
  int o  = np / SKK, kk = np % SKK;
  float v = 0.f;
  if(kk < 64)       v = en2w[((size_t)(i*64+o))*64 + kk];
  else if(kk == 64) v = en2b[i*64+o];
  W2b[idx] = f2b(v);
}

// ---------------- packed coalesced weights for k_node ----------------
__global__ __launch_bounds__(256) void k_packRoot(const float* __restrict__ root, float4* __restrict__ rootP){
  int idx = blockIdx.x*256 + threadIdx.x;
  if(idx >= 1024) return;
  int o = idx & 63, j4 = idx >> 6;
  float4 v;
  v.x = root[(4*j4+0)*64 + o];
  v.y = root[(4*j4+1)*64 + o];
  v.z = root[(4*j4+2)*64 + o];
  v.w = root[(4*j4+3)*64 + o];
  rootP[idx] = v;
}

__global__ __launch_bounds__(256) void k_packGates(const float* __restrict__ wih, const float* __restrict__ whh,
                                                   float4* __restrict__ wihP, float4* __restrict__ whhP){
  int idx = blockIdx.x*256 + threadIdx.x;
  if(idx >= 3072) return;
  int o = idx & 63, j4 = (idx >> 6) & 15, g = idx >> 10;
  int row = (g*64 + o)*64 + 4*j4;
  float4 a, b;
  a.x = wih[row+0]; a.y = wih[row+1]; a.z = wih[row+2]; a.w = wih[row+3];
  b.x = whh[row+0]; b.y = whh[row+1]; b.z = whh[row+2]; b.w = whh[row+3];
  wihP[idx] = a; whhP[idx] = b;
}

// ---------------- deg/cnt ----------------
__global__ __launch_bounds__(256) void k_degcnt(const int* __restrict__ ei,
                                                float* __restrict__ deg, int* __restrict__ cnt){
  int e = blockIdx.x*256 + threadIdx.x;
  if(e < N_EDGES){
    atomicAdd(&deg[ei[N_EDGES + e]], 1.0f);
    atomicAdd(&cnt[ei[e]], 1);
  }
}

// ---------------- scan ----------------
__global__ __launch_bounds__(1024) void k_scan(const int* __restrict__ cnt,
                                               int* __restrict__ offs, int* __restrict__ pos){
  __shared__ int s[1024];
  int t = threadIdx.x;
  int base = t*15;
  int c[15];
  int loc = 0;
  #pragma unroll
  for(int i=0;i<15;i++){ int idx=base+i; int v=(idx<N_NODES)?cnt[idx]:0; c[i]=v; loc+=v; }
  s[t]=loc; __syncthreads();
  for(int d=1; d<1024; d<<=1){
    int v2 = (t>=d)? s[t-d] : 0;
    __syncthreads();
    s[t] += v2;
    __syncthreads();
  }
  int run = s[t]-loc;
  #pragma unroll
  for(int i=0;i<15;i++){
    int idx=base+i;
    if(idx<N_NODES){ offs[idx]=run; pos[idx]=run; }
    run += c[i];
  }
  if(t==1023) offs[N_NODES]=s[1023];
}

// ---------------- CSR fill ----------------
__global__ __launch_bounds__(256) void k_fill(const int* __restrict__ ei,
                                              int* __restrict__ pos, int* __restrict__ eidx){
  int e = blockIdx.x*256 + threadIdx.x;
  if(e < N_EDGES){
    int slot = atomicAdd(&pos[ei[e]], 1);
    eidx[slot] = e;
  }
}

// ---------------- fused v2: MFMA M-build + barrier-free edge scatter ----------------
// Block: 8 nodes, 512 threads = 8 waves. GEMM [16(m, 8 real)×64(i)] @ [64×NPRIME] in bf16 MFMA.
// C rounded to bf16 in LDS Ml[node][o][kk]; edge phase: wave-strided edges, lane o contracts a1·Ml.
__global__ __launch_bounds__(512, 1) void k_fused(const float* __restrict__ outF, const float* __restrict__ a1,
                                               const u16* __restrict__ W2b,
                                               const int* __restrict__ ei,
                                               const int* __restrict__ offs, const int* __restrict__ eidx,
                                               float* __restrict__ agg){
  int l = threadIdx.x & 63;      // lane
  int w = threadIdx.x >> 6;      // wave 0..7
  int nb = blockIdx.x * 8;
  __shared__ float outs[8][64];
  __shared__ u16 Ml[8*64*SKK];   // [(m*64+o)*SKK + kk], 69632 B

  {
    int t = threadIdx.x;
    outs[t>>6][t&63] = outF[(size_t)(nb + (t>>6))*64 + (t&63)];
  }
  __syncthreads();

  // A fragments: A[m=lane&15][i=quad*8+j] (+32 for frag 1); rows 8..15 zero
  int m = l & 15, q = l >> 4;
  frag8 afrag[2];
  #pragma unroll
  for(int f=0; f<2; f++){
    #pragma unroll
    for(int j=0;j<8;j++){
      float v = (m < 8) ? outs[m][f*32 + q*8 + j] : 0.f;
      afrag[f][j] = (short)f2b(v);
    }
  }

  facc4 acc[TILES];
  #pragma unroll
  for(int tt=0;tt<TILES;tt++) acc[tt] = (facc4){0.f,0.f,0.f,0.f};

  int nbase = w * (NPRIME/8);
  #pragma unroll
  for(int tt=0; tt<TILES; tt++){
    int np = nbase + tt*16 + m;
    frag8 b0 = *(const frag8*)(W2b + ((size_t)q      *NPRIME + np)*8);
    frag8 b1 = *(const frag8*)(W2b + ((size_t)(q + 4)*NPRIME + np)*8);
    acc[tt] = __builtin_amdgcn_mfma_f32_16x16x32_bf16(afrag[0], b0, acc[tt], 0,0,0);
    acc[tt] = __builtin_amdgcn_mfma_f32_16x16x32_bf16(afrag[1], b1, acc[tt], 0,0,0);
  }

  // C/D: col = lane&15 (n'), row = quad*4 + reg (node). Keep rows < 8.
  #pragma unroll
  for(int tt=0;tt<TILES;tt++){
    int np = nbase + tt*16 + m;
    int o = np / SKK, kk = np % SKK;
    #pragma unroll
    for(int r=0;r<4;r++){
      int mr = q*4 + r;
      if(mr < 8) Ml[(mr*64 + o)*SKK + kk] = f2b(acc[tt][r]);
    }
  }
  __syncthreads();

  // edge phase: wave w takes edges lo+w, lo+w+8, ... ; no barriers
  int lo = offs[nb], hi = offs[nb+8];
  for(int s = lo + w; s < hi; s += 8){
    int e = eidx[s];
    int src = ei[e], dst = ei[N_EDGES + e];
    int nl = src - nb;
    const float4*   ap = (const float4*)(a1 + (size_t)e*KP);
    const ushort4*  mp = (const ushort4*)(Ml + ((size_t)nl*64 + l)*SKK);
    float p = 0.f;
    #pragma unroll
    for(int qq=0; qq<17; qq++){
      float4 a4 = ap[qq];
      ushort4 m4 = mp[qq];
      p += a4.x*u2f(m4.x) + a4.y*u2f(m4.y) + a4.z*u2f(m4.z) + a4.w*u2f(m4.w);
    }
    atomicAdd(&agg[(size_t)dst*64 + l], p);
  }
}

// ---------------- node update v6 (unchanged from round 8) ----------------
__global__ __launch_bounds__(256, 2) void k_node(const float* __restrict__ agg, const float* __restrict__ deg,
                                              float* __restrict__ outF,
                                              const float4* __restrict__ rootP, const float* __restrict__ convb,
                                              const float4* __restrict__ wihP, const float4* __restrict__ whhP,
                                              const float* __restrict__ bih, const float* __restrict__ bhh){
  int o = threadIdx.x & 63, g = threadIdx.x >> 6;
  int n = blockIdx.x * 4 + g;
  __shared__ __align__(16) float outs[4][64], ms[4][64];
  outs[g][o] = outF[(size_t)n*64+o];
  __syncthreads();

  const float4* op = (const float4*)outs[g];
  float acc = agg[(size_t)n*64+o] / fmaxf(deg[n], 1.0f) + convb[o];
  #pragma unroll 8
  for(int j4=0;j4<16;j4++){
    float4 w = rootP[j4*64+o];
    float4 m = op[j4];
    acc += w.x*m.x + w.y*m.y + w.z*m.z + w.w*m.w;
  }
  ms[g][o] = lrelu(acc);
  __syncthreads();

  float ir = bih[o], iz = bih[64+o], in_ = bih[128+o];
  float hr = bhh[o], hz = bhh[64+o], hn  = bhh[128+o];
  const float4* mp = (const float4*)ms[g];
  #pragma unroll 4
  for(int j4=0;j4<16;j4++){
    float4 m4 = mp[j4], h4 = op[j4];
    float4 a;
    a = wihP[(0*16+j4)*64+o]; ir  += m4.x*a.x+m4.y*a.y+m4.z*a.z+m4.w*a.w;
    a = wihP[(1*16+j4)*64+o]; iz  += m4.x*a.x+m4.y*a.y+m4.z*a.z+m4.w*a.w;
    a = wihP[(2*16+j4)*64+o]; in_ += m4.x*a.x+m4.y*a.y+m4.z*a.z+m4.w*a.w;
    a = whhP[(0*16+j4)*64+o]; hr  += h4.x*a.x+h4.y*a.y+h4.z*a.z+h4.w*a.w;
    a = whhP[(1*16+j4)*64+o]; hz  += h4.x*a.x+h4.y*a.y+h4.z*a.z+h4.w*a.w;
    a = whhP[(2*16+j4)*64+o]; hn  += h4.x*a.x+h4.y*a.y+h4.z*a.z+h4.w*a.w;
  }
  float r  = sigmoidf(ir+hr);
  float z  = sigmoidf(iz+hz);
  float ng = tanhf(in_ + r*hn);
  float hnew = (1.f - z)*ng + z*outs[g][o];
  if(n < N_NODES) outF[(size_t)n*64+o] = hnew;
}

// ---------------- stem head ----------------
__global__ __launch_bounds__(128) void k_stem(const float* __restrict__ outF, const int* __restrict__ sidx,
                                              const float* __restrict__ s1w, const float* __restrict__ s1b,
                                              const float* __restrict__ s2w, const float* __restrict__ s2b,
                                              void* __restrict__ dout, const int* __restrict__ flag){
  int s = blockIdx.x, t = threadIdx.x;
  int isf = *flag;
  __shared__ __align__(16) float xs[64], hid[64];
  int a = sidx[s];
  if(t<64) xs[t] = outF[a*64+t];
  __syncthreads();
  if(t<64) hid[t] = lrelu(s1b[t] + dot64_f(s1w + t*64, (const float4*)xs));
  __syncthreads();
  if(t<105){
    float acc = s2b[t] + dot64_f(s2w + t*64, (const float4*)hid);
    store_out(dout, isf, OUT_STEM + s*105 + t, acc);
  }
}

// ---------------- jbond head ----------------
__global__ __launch_bounds__(128) void k_jbond(const float* __restrict__ outF, const int* __restrict__ jidx,
                                               const float* __restrict__ j1w, const float* __restrict__ j1b,
                                               const float* __restrict__ j2w, const float* __restrict__ j2b,
                                               void* __restrict__ dout, const int* __restrict__ flag){
  int jb = blockIdx.x, t = threadIdx.x;
  int isf = *flag;
  __shared__ __align__(16) float xs[2][64], hid[2][64];
  int at = t>>6, k = t&63;
  int a = jidx[jb*2 + at];
  xs[at][k] = outF[a*64+k];
  __syncthreads();
  hid[at][k] = lrelu(j1b[k] + dot64_f(j1w + k*64, (const float4*)xs[at]));
  __syncthreads();
  if(t<64){
    float p = (hid[0][t] + hid[1][t]) * j2w[t];
    #pragma unroll
    for(int s=32;s;s>>=1) p += __shfl_xor(p, s, 64);
    if(t==0) store_out(dout, isf, OUT_JB + jb, 0.5f*p + j2b[0]);
  }
}

// ---------------- Set2Set + final linear ----------------
__global__ __launch_bounds__(64) void k_s2s(const float* __restrict__ outF, const int* __restrict__ batch,
                                            const float* __restrict__ bih, const float* __restrict__ bhh,
                                            const float* __restrict__ loutw, const float* __restrict__ loutb,
                                            void* __restrict__ dout, const int* __restrict__ flag){
  int b = blockIdx.x, t = threadIdx.x;
  int isf = *flag;
  float i_ = bih[t]     + bhh[t];
  float g_ = bih[128+t] + bhh[128+t];
  float o_ = bih[192+t] + bhh[192+t];
  float c  = sigmoidf(i_)*tanhf(g_);
  float q  = sigmoidf(o_)*tanhf(c);

  int lo = lower_bound_i(batch, N_NODES, b);
  int hi = lower_bound_i(batch, N_NODES, b+1);

  float emax = -3.4e38f;
  for(int n=lo;n<hi;n++){
    float p = outF[n*64+t]*q;
    #pragma unroll
    for(int s=32;s;s>>=1) p += __shfl_xor(p, s, 64);
    emax = fmaxf(emax, p);
  }
  float Z = 0.f, racc = 0.f;
  for(int n=lo;n<hi;n++){
    float v = outF[n*64+t];
    float p = v*q;
    #pragma unroll
    for(int s=32;s;s>>=1) p += __shfl_xor(p, s, 64);
    float w = expf(p - emax);
    Z += w; racc += w*v;
  }
  float rp = (hi>lo) ? racc/Z : 0.f;

  #pragma unroll
  for(int j=0;j<2;j++){
    float p = q*loutw[j*128+t] + rp*loutw[j*128+64+t];
    #pragma unroll
    for(int s=32;s;s>>=1) p += __shfl_xor(p, s, 64);
    if(t==0) store_out(dout, isf, OUT_FINAL + b*2 + j, p + loutb[j]);
  }
}

extern "C" void kernel_launch(void* const* d_in, const int* in_sizes, int n_in,
                              void* d_out, int out_size, void* d_ws, size_t ws_size,
                              hipStream_t stream) {
  const int* edge_index  = (const int*)d_in[28];
  const int* stem_atmidx = (const int*)d_in[29];
  const int* jbond_atmidx= (const int*)d_in[30];
  const int* batch       = (const int*)d_in[31];

  char* ws = (char*)d_ws;
  size_t off = 0;
  auto alloc = [&](size_t bytes)->void*{ void* p = ws + off; off = (off + bytes + 255) & ~(size_t)255; return p; };

  int*   flag = (int*)  alloc(4);
  float* outF = (float*)alloc((size_t)PADN*64*4);
  float* agg  = (float*)alloc((size_t)PADN*64*4);
  float* a1   = (float*)alloc((size_t)N_EDGES*KP*4);
  u16*   W2b  = (u16*)  alloc((size_t)8*NPRIME*8*2);     // 540 KB bf16 B operand
  float* deg  = (float*)alloc((size_t)PADN*4);
  int*   cnt  = (int*)  alloc((size_t)N_NODES*4);
  int*   offs = (int*)  alloc((size_t)(N_NODES+1)*4);
  int*   pos  = (int*)  alloc((size_t)N_NODES*4);
  int*   eidx = (int*)  alloc((size_t)N_EDGES*4);
  float4* rootP = (float4*)alloc(1024*16);
  float4* wihP  = (float4*)alloc(3072*16);
  float4* whhP  = (float4*)alloc(3072*16);

  static const int cvt_idx[N_CVT] = {0,1,2,3,4,5,6,7,8,9,10,11,12,13,14,15,16,17,18,19,20,21,24,25,26,27};
  CvtArgs A;
  float* cF[N_CVT];
  for(int i=0;i<N_CVT;i++){
    int src = cvt_idx[i];
    int n = in_sizes[src];
    cF[i] = (float*)alloc((size_t)n*4);
    A.src[i] = d_in[src];
    A.dst[i] = cF[i];
    A.n[i]   = n;
  }
  (void)ws_size; (void)n_in; (void)out_size;
  float* xF=cF[0];   float* eaF=cF[1];  float* l0w=cF[2];  float* l0b=cF[3];
  float* e1w=cF[4];  float* e1b=cF[5];  float* e2w=cF[6];  float* e2b=cF[7];
  float* rootw=cF[8];float* convb=cF[9];
  float* wih=cF[10]; float* whh=cF[11]; float* bih=cF[12]; float* bhh=cF[13];
  float* s1w=cF[14]; float* s1b=cF[15]; float* s2w=cF[16]; float* s2b=cF[17];
  float* j1w=cF[18]; float* j1b=cF[19]; float* j2w=cF[20]; float* j2b=cF[21];
  float* lbih=cF[22];float* lbhh=cF[23];float* loutw=cF[24];float* loutb=cF[25];

  hipMemsetAsync(flag, 0, 4, stream);
  hipMemsetAsync(deg,  0, (size_t)PADN*4, stream);
  hipMemsetAsync(cnt,  0, (size_t)N_NODES*4, stream);
  hipMemsetAsync(outF + (size_t)N_NODES*64, 0, (size_t)(PADN-N_NODES)*64*4, stream);

  k_sniff <<<128, 256, 0, stream>>>((const u16*)d_in[0], in_sizes[0], flag);
  k_cvt   <<<512, 256, 0, stream>>>(A, flag);

  k_lin0    <<<N_NODES, 64, 0, stream>>>(xF, l0w, l0b, outF);
  k_a1      <<<N_EDGES, 128, 0, stream>>>(eaF, e1w, e1b, a1);
  k_packW2b <<<(8*NPRIME*8+255)/256, 256, 0, stream>>>(e2w, e2b, W2b);
  k_packRoot<<<4, 256, 0, stream>>>(rootw, rootP);
  k_packGates<<<12, 256, 0, stream>>>(wih, whh, wihP, whhP);
  k_degcnt  <<<(N_EDGES+255)/256, 256, 0, stream>>>(edge_index, deg, cnt);
  k_scan    <<<1, 1024, 0, stream>>>(cnt, offs, pos);
  k_fill    <<<(N_EDGES+255)/256, 256, 0, stream>>>(edge_index, pos, eidx);

  for(int it=0; it<6; it++){
    hipMemsetAsync(agg, 0, (size_t)PADN*64*4, stream);
    k_fused<<<N_NODES/8, 512, 0, stream>>>(outF, a1, W2b, edge_index, offs, eidx, agg);
    k_node <<<PADN/4, 256, 0, stream>>>(agg, deg, outF, rootP, convb, wihP, whhP, bih, bhh);
  }

  k_stem <<<N_STEMS, 128, 0, stream>>>(outF, stem_atmidx, s1w, s1b, s2w, s2b, d_out, flag);
  k_jbond<<<N_JBONDS, 128, 0, stream>>>(outF, jbond_atmidx, j1w, j1b, j2w, j2b, d_out, flag);
  k_s2s  <<<NUM_GRAPHS, 64, 0, stream>>>(outF, batch, lbih, lbhh, loutw, loutb, d_out, flag);
}

// Round 10
// 940.990 us; speedup vs baseline: 5.0473x; 1.3524x over previous
//
#include <hip/hip_runtime.h>

typedef unsigned short u16;
typedef unsigned int   u32;

#define N_NODES    15000
#define PADN       15008
#define N_EDGES    30000
#define NUM_GRAPHS 600
#define N_STEMS    6000
#define N_JBONDS   3000

#define OUT_FINAL  0
#define OUT_STEM   1200
#define OUT_JB     631200

#define KP 72                 // a1 K-extent (64 + bias + pad)
#define SKK 68                // B-operand n' packing: n' = o*68 + kk
#define NPRIME (64*SKK)       // 4352
#define TILES ((NPRIME/8)/16) // 34 tiles per wave
#define NODESB 16             // nodes per k_fused block
#define NSTR 4356             // Ml node stride in u16: 64*68+4 (2178 dw == 2 mod 32)
#define N_CVT 26

typedef short frag8 __attribute__((ext_vector_type(8)));   // 8 bf16
typedef float facc4 __attribute__((ext_vector_type(4)));   // 4 f32 acc

__device__ __forceinline__ float u2f(u16 v){ union{u32 i; float f;} c; c.i=((u32)v)<<16; return c.f; }
__device__ __forceinline__ u16  f2b(float f){ union{float f; u32 u;} c; c.f=f; u32 u=c.u;
                                              return (u16)((u + 0x7fffu + ((u>>16)&1u))>>16); }
__device__ __forceinline__ float lrelu(float x){ return x>0.f ? x : 0.01f*x; }
__device__ __forceinline__ float sigmoidf(float x){ return 1.f/(1.f+expf(-x)); }

__device__ __forceinline__ float dot64_f(const float* __restrict__ w, const float4* __restrict__ x4){
  const float4* wp = (const float4*)w;
  float acc = 0.f;
  #pragma unroll
  for(int c=0;c<16;c++){ float4 a=wp[c], b=x4[c]; acc += a.x*b.x+a.y*b.y+a.z*b.z+a.w*b.w; }
  return acc;
}

__device__ __forceinline__ int lower_bound_i(const int* __restrict__ a, int n, int v){
  int lo=0, hi=n;
  while(lo<hi){ int m=(lo+hi)>>1; if(a[m]<v) lo=m+1; else hi=m; }
  return lo;
}

__device__ __forceinline__ void store_out(void* dout, int isf, int idx, float v){
  if(isf) ((float*)dout)[idx] = v;
  else    ((u16*)dout)[idx]   = f2b(v);
}

// ---------------- dtype sniff ----------------
__global__ __launch_bounds__(256) void k_sniff(const u16* __restrict__ x, int n, int* __restrict__ flag){
  int i = blockIdx.x*256 + threadIdx.x;
  int local = 0;
  for(; i < n; i += gridDim.x*256){
    u16 v = x[i];
    if(((v>>7)&0xFFu) == 0xFFu) local = 1;
  }
  if(local) atomicOr(flag, 1);
}

// ---------------- convert float inputs to f32 ----------------
struct CvtArgs { const void* src[N_CVT]; float* dst[N_CVT]; int n[N_CVT]; };

__global__ __launch_bounds__(256) void k_cvt(CvtArgs A, const int* __restrict__ flag){
  int isf = *flag;
  int tid = blockIdx.x*256 + threadIdx.x;
  int stride = gridDim.x*256;
  for(int b=0; b<N_CVT; b++){
    int n = A.n[b];
    const float* sf = (const float*)A.src[b];
    const u16*   sb = (const u16*)A.src[b];
    float* d = A.dst[b];
    for(int i=tid; i<n; i+=stride) d[i] = isf ? sf[i] : u2f(sb[i]);
  }
}

// ---------------- lin0 ----------------
__global__ __launch_bounds__(64) void k_lin0(const float* __restrict__ x, const float* __restrict__ w,
                                             const float* __restrict__ b,
                                             float* __restrict__ outF){
  int n = blockIdx.x, o = threadIdx.x;
  __shared__ float xs[14];
  if(o<14) xs[o] = x[n*14+o];
  __syncthreads();
  float acc = b[o];
  #pragma unroll
  for(int i=0;i<14;i++) acc += xs[i]*w[o*14+i];
  outF[n*64+o] = lrelu(acc);
}

// ---------------- a1~[e][KP] ----------------
__global__ __launch_bounds__(128) void k_a1(const float* __restrict__ ea,
                                            const float* __restrict__ en1w, const float* __restrict__ en1b,
                                            float* __restrict__ a1){
  int e = blockIdx.x, k = threadIdx.x;
  if(k >= KP) return;
  float v;
  if(k < 64){
    float acc = en1b[k];
    #pragma unroll
    for(int c=0;c<4;c++) acc += ea[e*4+c] * en1w[k*4+c];
    v = lrelu(acc);
  } else v = (k==64) ? 1.0f : 0.0f;
  a1[(size_t)e*KP + k] = v;
}

// ---------------- W2b: bf16 B-operand, fragment-ordered ----------------
__global__ __launch_bounds__(256) void k_packW2b(const float* __restrict__ en2w, const float* __restrict__ en2b,
                                                 u16* __restrict__ W2b){
  int idx = blockIdx.x*256 + threadIdx.x;
  if(idx >= 8*NPRIME*8) return;
  int j  = idx & 7;
  int np = (idx >> 3) % NPRIME;
  int Kc = idx / (NPRIME*8);
  int i  = Kc*8 + j;
  int o  = np / SKK, kk = np % SKK;
  float v = 0.f;
  if(kk < 64)       v = en2w[((size_t)(i*64+o))*64 + kk];
  else if(kk == 64) v = en2b[i*64+o];
  W2b[idx] = f2b(v);
}

// ---------------- packed coalesced weights for k_node ----------------
__global__ __launch_bounds__(256) void k_packRoot(const float* __restrict__ root, float4* __restrict__ rootP){
  int idx = blockIdx.x*256 + threadIdx.x;
  if(idx >= 1024) return;
  int o = idx & 63, j4 = idx >> 6;
  float4 v;
  v.x = root[(4*j4+0)*64 + o];
  v.y = root[(4*j4+1)*64 + o];
  v.z = root[(4*j4+2)*64 + o];
  v.w = root[(4*j4+3)*64 + o];
  rootP[idx] = v;
}

__global__ __launch_bounds__(256) void k_packGates(const float* __restrict__ wih, const float* __restrict__ whh,
                                                   float4* __restrict__ wihP, float4* __restrict__ whhP){
  int idx = blockIdx.x*256 + threadIdx.x;
  if(idx >= 3072) return;
  int o = idx & 63, j4 = (idx >> 6) & 15, g = idx >> 10;
  int row = (g*64 + o)*64 + 4*j4;
  float4 a, b;
  a.x = wih[row+0]; a.y = wih[row+1]; a.z = wih[row+2]; a.w = wih[row+3];
  b.x = whh[row+0]; b.y = whh[row+1]; b.z = whh[row+2]; b.w = whh[row+3];
  wihP[idx] = a; whhP[idx] = b;
}

// ---------------- deg/cnt ----------------
__global__ __launch_bounds__(256) void k_degcnt(const int* __restrict__ ei,
                                                float* __restrict__ deg, int* __restrict__ cnt){
  int e = blockIdx.x*256 + threadIdx.x;
  if(e < N_EDGES){
    atomicAdd(&deg[ei[N_EDGES + e]], 1.0f);
    atomicAdd(&cnt[ei[e]], 1);
  }
}

// ---------------- scan (offs extended through PADN) ----------------
__global__ __launch_bounds__(1024) void k_scan(const int* __restrict__ cnt,
                                               int* __restrict__ offs, int* __restrict__ pos){
  __shared__ int s[1024];
  int t = threadIdx.x;
  int base = t*15;
  int c[15];
  int loc = 0;
  #pragma unroll
  for(int i=0;i<15;i++){ int idx=base+i; int v=(idx<N_NODES)?cnt[idx]:0; c[i]=v; loc+=v; }
  s[t]=loc; __syncthreads();
  for(int d=1; d<1024; d<<=1){
    int v2 = (t>=d)? s[t-d] : 0;
    __syncthreads();
    s[t] += v2;
    __syncthreads();
  }
  int run = s[t]-loc;
  #pragma unroll
  for(int i=0;i<15;i++){
    int idx=base+i;
    if(idx<N_NODES){ offs[idx]=run; pos[idx]=run; }
    run += c[i];
  }
  if(t==1023){
    for(int idx=N_NODES; idx<=PADN; idx++) offs[idx] = s[1023];
  }
}

// ---------------- CSR fill ----------------
__global__ __launch_bounds__(256) void k_fill(const int* __restrict__ ei,
                                              int* __restrict__ pos, int* __restrict__ eidx){
  int e = blockIdx.x*256 + threadIdx.x;
  if(e < N_EDGES){
    int slot = atomicAdd(&pos[ei[e]], 1);
    eidx[slot] = e;
  }
}

// ---------------- fused v3: 16-node MFMA M-build + conflict-free Ml + edge scatter ----------------
// Block: 16 nodes, 512 threads = 8 waves. GEMM [16(m)×64(i)] @ [64×NPRIME] bf16 MFMA.
// Ml[node][o][kk] at node*NSTR + o*68 + kk (u16). NSTR=4356: stores conflict-free
// (quads land on banks {0,8,16,24}), reads 8B-aligned ushort4.
__global__ __launch_bounds__(512, 1) void k_fused(const float* __restrict__ outF, const float* __restrict__ a1,
                                               const u16* __restrict__ W2b,
                                               const int* __restrict__ ei,
                                               const int* __restrict__ offs, const int* __restrict__ eidx,
                                               float* __restrict__ agg){
  int l = threadIdx.x & 63;      // lane
  int w = threadIdx.x >> 6;      // wave 0..7
  int nb = blockIdx.x * NODESB;
  __shared__ float outs[NODESB][64];
  __shared__ u16 Ml[NODESB*NSTR];   // 139,392 B

  {
    int t = threadIdx.x;
    #pragma unroll
    for(int r=0;r<2;r++){
      int idx = t + r*512;          // 0..1023
      outs[idx>>6][idx&63] = outF[(size_t)(nb + (idx>>6))*64 + (idx&63)];
    }
  }
  __syncthreads();

  // A fragments: A[m=lane&15][i=quad*8+j] (+32 for frag 1); all 16 rows real
  int m = l & 15, q = l >> 4;
  frag8 afrag[2];
  #pragma unroll
  for(int f=0; f<2; f++){
    #pragma unroll
    for(int j=0;j<8;j++){
      afrag[f][j] = (short)f2b(outs[m][f*32 + q*8 + j]);
    }
  }

  facc4 acc[TILES];
  #pragma unroll
  for(int tt=0;tt<TILES;tt++) acc[tt] = (facc4){0.f,0.f,0.f,0.f};

  int nbase = w * (NPRIME/8);
  #pragma unroll
  for(int tt=0; tt<TILES; tt++){
    int np = nbase + tt*16 + m;
    frag8 b0 = *(const frag8*)(W2b + ((size_t)q      *NPRIME + np)*8);
    frag8 b1 = *(const frag8*)(W2b + ((size_t)(q + 4)*NPRIME + np)*8);
    acc[tt] = __builtin_amdgcn_mfma_f32_16x16x32_bf16(afrag[0], b0, acc[tt], 0,0,0);
    acc[tt] = __builtin_amdgcn_mfma_f32_16x16x32_bf16(afrag[1], b1, acc[tt], 0,0,0);
  }

  // C/D: col = lane&15 (n'), row = quad*4 + reg (node 0..15)
  #pragma unroll
  for(int tt=0;tt<TILES;tt++){
    int np = nbase + tt*16 + m;
    int o = np / SKK, kk = np % SKK;
    #pragma unroll
    for(int r=0;r<4;r++){
      int mr = q*4 + r;
      Ml[mr*NSTR + o*SKK + kk] = f2b(acc[tt][r]);
    }
  }
  __syncthreads();

  // edge phase: wave w takes edges lo+w, lo+w+8, ...
  int lo = offs[nb], hi = offs[nb+NODESB];
  for(int s = lo + w; s < hi; s += 8){
    int e = eidx[s];
    int src = ei[e], dst = ei[N_EDGES + e];
    int nl = src - nb;
    const float4*   ap = (const float4*)(a1 + (size_t)e*KP);
    const ushort4*  mp = (const ushort4*)(Ml + (size_t)nl*NSTR + l*SKK);
    float p = 0.f;
    #pragma unroll
    for(int qq=0; qq<17; qq++){
      float4 a4 = ap[qq];
      ushort4 m4 = mp[qq];
      p += a4.x*u2f(m4.x) + a4.y*u2f(m4.y) + a4.z*u2f(m4.z) + a4.w*u2f(m4.w);
    }
    atomicAdd(&agg[(size_t)dst*64 + l], p);
  }
}

// ---------------- node update (unchanged) ----------------
__global__ __launch_bounds__(256, 2) void k_node(const float* __restrict__ agg, const float* __restrict__ deg,
                                              float* __restrict__ outF,
                                              const float4* __restrict__ rootP, const float* __restrict__ convb,
                                              const float4* __restrict__ wihP, const float4* __restrict__ whhP,
                                              const float* __restrict__ bih, const float* __restrict__ bhh){
  int o = threadIdx.x & 63, g = threadIdx.x >> 6;
  int n = blockIdx.x * 4 + g;
  __shared__ __align__(16) float outs[4][64], ms[4][64];
  outs[g][o] = outF[(size_t)n*64+o];
  __syncthreads();

  const float4* op = (const float4*)outs[g];
  float acc = agg[(size_t)n*64+o] / fmaxf(deg[n], 1.0f) + convb[o];
  #pragma unroll 8
  for(int j4=0;j4<16;j4++){
    float4 w = rootP[j4*64+o];
    float4 m = op[j4];
    acc += w.x*m.x + w.y*m.y + w.z*m.z + w.w*m.w;
  }
  ms[g][o] = lrelu(acc);
  __syncthreads();

  float ir = bih[o], iz = bih[64+o], in_ = bih[128+o];
  float hr = bhh[o], hz = bhh[64+o], hn  = bhh[128+o];
  const float4* mp = (const float4*)ms[g];
  #pragma unroll 4
  for(int j4=0;j4<16;j4++){
    float4 m4 = mp[j4], h4 = op[j4];
    float4 a;
    a = wihP[(0*16+j4)*64+o]; ir  += m4.x*a.x+m4.y*a.y+m4.z*a.z+m4.w*a.w;
    a = wihP[(1*16+j4)*64+o]; iz  += m4.x*a.x+m4.y*a.y+m4.z*a.z+m4.w*a.w;
    a = wihP[(2*16+j4)*64+o]; in_ += m4.x*a.x+m4.y*a.y+m4.z*a.z+m4.w*a.w;
    a = whhP[(0*16+j4)*64+o]; hr  += h4.x*a.x+h4.y*a.y+h4.z*a.z+h4.w*a.w;
    a = whhP[(1*16+j4)*64+o]; hz  += h4.x*a.x+h4.y*a.y+h4.z*a.z+h4.w*a.w;
    a = whhP[(2*16+j4)*64+o]; hn  += h4.x*a.x+h4.y*a.y+h4.z*a.z+h4.w*a.w;
  }
  float r  = sigmoidf(ir+hr);
  float z  = sigmoidf(iz+hz);
  float ng = tanhf(in_ + r*hn);
  float hnew = (1.f - z)*ng + z*outs[g][o];
  if(n < N_NODES) outF[(size_t)n*64+o] = hnew;
}

// ---------------- stem head ----------------
__global__ __launch_bounds__(128) void k_stem(const float* __restrict__ outF, const int* __restrict__ sidx,
                                              const float* __restrict__ s1w, const float* __restrict__ s1b,
                                              const float* __restrict__ s2w, const float* __restrict__ s2b,
                                              void* __restrict__ dout, const int* __restrict__ flag){
  int s = blockIdx.x, t = threadIdx.x;
  int isf = *flag;
  __shared__ __align__(16) float xs[64], hid[64];
  int a = sidx[s];
  if(t<64) xs[t] = outF[a*64+t];
  __syncthreads();
  if(t<64) hid[t] = lrelu(s1b[t] + dot64_f(s1w + t*64, (const float4*)xs));
  __syncthreads();
  if(t<105){
    float acc = s2b[t] + dot64_f(s2w + t*64, (const float4*)hid);
    store_out(dout, isf, OUT_STEM + s*105 + t, acc);
  }
}

// ---------------- jbond head ----------------
__global__ __launch_bounds__(128) void k_jbond(const float* __restrict__ outF, const int* __restrict__ jidx,
                                               const float* __restrict__ j1w, const float* __restrict__ j1b,
                                               const float* __restrict__ j2w, const float* __restrict__ j2b,
                                               void* __restrict__ dout, const int* __restrict__ flag){
  int jb = blockIdx.x, t = threadIdx.x;
  int isf = *flag;
  __shared__ __align__(16) float xs[2][64], hid[2][64];
  int at = t>>6, k = t&63;
  int a = jidx[jb*2 + at];
  xs[at][k] = outF[a*64+k];
  __syncthreads();
  hid[at][k] = lrelu(j1b[k] + dot64_f(j1w + k*64, (const float4*)xs[at]));
  __syncthreads();
  if(t<64){
    float p = (hid[0][t] + hid[1][t]) * j2w[t];
    #pragma unroll
    for(int s=32;s;s>>=1) p += __shfl_xor(p, s, 64);
    if(t==0) store_out(dout, isf, OUT_JB + jb, 0.5f*p + j2b[0]);
  }
}

// ---------------- Set2Set + final linear ----------------
__global__ __launch_bounds__(64) void k_s2s(const float* __restrict__ outF, const int* __restrict__ batch,
                                            const float* __restrict__ bih, const float* __restrict__ bhh,
                                            const float* __restrict__ loutw, const float* __restrict__ loutb,
                                            void* __restrict__ dout, const int* __restrict__ flag){
  int b = blockIdx.x, t = threadIdx.x;
  int isf = *flag;
  float i_ = bih[t]     + bhh[t];
  float g_ = bih[128+t] + bhh[128+t];
  float o_ = bih[192+t] + bhh[192+t];
  float c  = sigmoidf(i_)*tanhf(g_);
  float q  = sigmoidf(o_)*tanhf(c);

  int lo = lower_bound_i(batch, N_NODES, b);
  int hi = lower_bound_i(batch, N_NODES, b+1);

  float emax = -3.4e38f;
  for(int n=lo;n<hi;n++){
    float p = outF[n*64+t]*q;
    #pragma unroll
    for(int s=32;s;s>>=1) p += __shfl_xor(p, s, 64);
    emax = fmaxf(emax, p);
  }
  float Z = 0.f, racc = 0.f;
  for(int n=lo;n<hi;n++){
    float v = outF[n*64+t];
    float p = v*q;
    #pragma unroll
    for(int s=32;s;s>>=1) p += __shfl_xor(p, s, 64);
    float w = expf(p - emax);
    Z += w; racc += w*v;
  }
  float rp = (hi>lo) ? racc/Z : 0.f;

  #pragma unroll
  for(int j=0;j<2;j++){
    float p = q*loutw[j*128+t] + rp*loutw[j*128+64+t];
    #pragma unroll
    for(int s=32;s;s>>=1) p += __shfl_xor(p, s, 64);
    if(t==0) store_out(dout, isf, OUT_FINAL + b*2 + j, p + loutb[j]);
  }
}

extern "C" void kernel_launch(void* const* d_in, const int* in_sizes, int n_in,
                              void* d_out, int out_size, void* d_ws, size_t ws_size,
                              hipStream_t stream) {
  const int* edge_index  = (const int*)d_in[28];
  const int* stem_atmidx = (const int*)d_in[29];
  const int* jbond_atmidx= (const int*)d_in[30];
  const int* batch       = (const int*)d_in[31];

  char* ws = (char*)d_ws;
  size_t off = 0;
  auto alloc = [&](size_t bytes)->void*{ void* p = ws + off; off = (off + bytes + 255) & ~(size_t)255; return p; };

  int*   flag = (int*)  alloc(4);
  float* outF = (float*)alloc((size_t)PADN*64*4);
  float* agg  = (float*)alloc((size_t)PADN*64*4);
  float* a1   = (float*)alloc((size_t)N_EDGES*KP*4);
  u16*   W2b  = (u16*)  alloc((size_t)8*NPRIME*8*2);     // 540 KB bf16 B operand
  float* deg  = (float*)alloc((size_t)PADN*4);
  int*   cnt  = (int*)  alloc((size_t)N_NODES*4);
  int*   offs = (int*)  alloc((size_t)(PADN+1)*4);
  int*   pos  = (int*)  alloc((size_t)N_NODES*4);
  int*   eidx = (int*)  alloc((size_t)N_EDGES*4);
  float4* rootP = (float4*)alloc(1024*16);
  float4* wihP  = (float4*)alloc(3072*16);
  float4* whhP  = (float4*)alloc(3072*16);

  static const int cvt_idx[N_CVT] = {0,1,2,3,4,5,6,7,8,9,10,11,12,13,14,15,16,17,18,19,20,21,24,25,26,27};
  CvtArgs A;
  float* cF[N_CVT];
  for(int i=0;i<N_CVT;i++){
    int src = cvt_idx[i];
    int n = in_sizes[src];
    cF[i] = (float*)alloc((size_t)n*4);
    A.src[i] = d_in[src];
    A.dst[i] = cF[i];
    A.n[i]   = n;
  }
  (void)ws_size; (void)n_in; (void)out_size;
  float* xF=cF[0];   float* eaF=cF[1];  float* l0w=cF[2];  float* l0b=cF[3];
  float* e1w=cF[4];  float* e1b=cF[5];  float* e2w=cF[6];  float* e2b=cF[7];
  float* rootw=cF[8];float* convb=cF[9];
  float* wih=cF[10]; float* whh=cF[11]; float* bih=cF[12]; float* bhh=cF[13];
  float* s1w=cF[14]; float* s1b=cF[15]; float* s2w=cF[16]; float* s2b=cF[17];
  float* j1w=cF[18]; float* j1b=cF[19]; float* j2w=cF[20]; float* j2b=cF[21];
  float* lbih=cF[22];float* lbhh=cF[23];float* loutw=cF[24];float* loutb=cF[25];

  hipMemsetAsync(flag, 0, 4, stream);
  hipMemsetAsync(deg,  0, (size_t)PADN*4, stream);
  hipMemsetAsync(cnt,  0, (size_t)N_NODES*4, stream);
  hipMemsetAsync(outF + (size_t)N_NODES*64, 0, (size_t)(PADN-N_NODES)*64*4, stream);

  k_sniff <<<128, 256, 0, stream>>>((const u16*)d_in[0], in_sizes[0], flag);
  k_cvt   <<<512, 256, 0, stream>>>(A, flag);

  k_lin0    <<<N_NODES, 64, 0, stream>>>(xF, l0w, l0b, outF);
  k_a1      <<<N_EDGES, 128, 0, stream>>>(eaF, e1w, e1b, a1);
  k_packW2b <<<(8*NPRIME*8+255)/256, 256, 0, stream>>>(e2w, e2b, W2b);
  k_packRoot<<<4, 256, 0, stream>>>(rootw, rootP);
  k_packGates<<<12, 256, 0, stream>>>(wih, whh, wihP, whhP);
  k_degcnt  <<<(N_EDGES+255)/256, 256, 0, stream>>>(edge_index, deg, cnt);
  k_scan    <<<1, 1024, 0, stream>>>(cnt, offs, pos);
  k_fill    <<<(N_EDGES+255)/256, 256, 0, stream>>>(edge_index, pos, eidx);

  for(int it=0; it<6; it++){
    hipMemsetAsync(agg, 0, (size_t)PADN*64*4, stream);
    k_fused<<<PADN/NODESB, 512, 0, stream>>>(outF, a1, W2b, edge_index, offs, eidx, agg);
    k_node <<<PADN/4, 256, 0, stream>>>(agg, deg, outF, rootP, convb, wihP, whhP, bih, bhh);
  }

  k_stem <<<N_STEMS, 128, 0, stream>>>(outF, stem_atmidx, s1w, s1b, s2w, s2b, d_out, flag);
  k_jbond<<<N_JBONDS, 128, 0, stream>>>(outF, jbond_atmidx, j1w, j1b, j2w, j2b, d_out, flag);
  k_s2s  <<<NUM_GRAPHS, 64, 0, stream>>>(outF, batch, lbih, lbhh, loutw, loutb, d_out, flag);
}

// Round 11
// 928.036 us; speedup vs baseline: 5.1177x; 1.0140x over previous
//
#include <hip/hip_runtime.h>

typedef unsigned short u16;
typedef unsigned int   u32;

#define N_NODES    15000
#define PADN       15008
#define N_EDGES    30000
#define NUM_GRAPHS 600
#define N_STEMS    6000
#define N_JBONDS   3000

#define OUT_FINAL  0
#define OUT_STEM   1200
#define OUT_JB     631200

#define KP 72                 // a1 K-extent (64 + bias + pad)
#define SKK 68                // B-operand n' packing: n' = o*68 + kk
#define NPRIME (64*SKK)       // 4352
#define TILES ((NPRIME/8)/16) // 34 tiles per wave
#define NODESB 16             // nodes per k_fused block
#define NSTR 4356             // Ml node stride in u16: 64*68+4 (2178 dw == 2 mod 32)
#define N_CVT 26

typedef short frag8 __attribute__((ext_vector_type(8)));   // 8 bf16
typedef float facc4 __attribute__((ext_vector_type(4)));   // 4 f32 acc

__device__ __forceinline__ float u2f(u16 v){ union{u32 i; float f;} c; c.i=((u32)v)<<16; return c.f; }
__device__ __forceinline__ u16  f2b(float f){ union{float f; u32 u;} c; c.f=f; u32 u=c.u;
                                              return (u16)((u + 0x7fffu + ((u>>16)&1u))>>16); }
__device__ __forceinline__ float lrelu(float x){ return x>0.f ? x : 0.01f*x; }
__device__ __forceinline__ float sigmoidf(float x){ return 1.f/(1.f+expf(-x)); }

__device__ __forceinline__ int lower_bound_i(const int* __restrict__ a, int n, int v){
  int lo=0, hi=n;
  while(lo<hi){ int m=(lo+hi)>>1; if(a[m]<v) lo=m+1; else hi=m; }
  return lo;
}

__device__ __forceinline__ void store_out(void* dout, int isf, int idx, float v){
  if(isf) ((float*)dout)[idx] = v;
  else    ((u16*)dout)[idx]   = f2b(v);
}

// ---------------- dtype sniff ----------------
__global__ __launch_bounds__(256) void k_sniff(const u16* __restrict__ x, int n, int* __restrict__ flag){
  int i = blockIdx.x*256 + threadIdx.x;
  int local = 0;
  for(; i < n; i += gridDim.x*256){
    u16 v = x[i];
    if(((v>>7)&0xFFu) == 0xFFu) local = 1;
  }
  if(local) atomicOr(flag, 1);
}

// ---------------- convert float inputs to f32 ----------------
struct CvtArgs { const void* src[N_CVT]; float* dst[N_CVT]; int n[N_CVT]; };

__global__ __launch_bounds__(256) void k_cvt(CvtArgs A, const int* __restrict__ flag){
  int isf = *flag;
  int tid = blockIdx.x*256 + threadIdx.x;
  int stride = gridDim.x*256;
  for(int b=0; b<N_CVT; b++){
    int n = A.n[b];
    const float* sf = (const float*)A.src[b];
    const u16*   sb = (const u16*)A.src[b];
    float* d = A.dst[b];
    for(int i=tid; i<n; i+=stride) d[i] = isf ? sf[i] : u2f(sb[i]);
  }
}

// ---------------- lin0 ----------------
__global__ __launch_bounds__(64) void k_lin0(const float* __restrict__ x, const float* __restrict__ w,
                                             const float* __restrict__ b,
                                             float* __restrict__ outF){
  int n = blockIdx.x, o = threadIdx.x;
  __shared__ float xs[14];
  if(o<14) xs[o] = x[n*14+o];
  __syncthreads();
  float acc = b[o];
  #pragma unroll
  for(int i=0;i<14;i++) acc += xs[i]*w[o*14+i];
  outF[n*64+o] = lrelu(acc);
}

// ---------------- a1~[e][KP] ----------------
__global__ __launch_bounds__(128) void k_a1(const float* __restrict__ ea,
                                            const float* __restrict__ en1w, const float* __restrict__ en1b,
                                            float* __restrict__ a1){
  int e = blockIdx.x, k = threadIdx.x;
  if(k >= KP) return;
  float v;
  if(k < 64){
    float acc = en1b[k];
    #pragma unroll
    for(int c=0;c<4;c++) acc += ea[e*4+c] * en1w[k*4+c];
    v = lrelu(acc);
  } else v = (k==64) ? 1.0f : 0.0f;
  a1[(size_t)e*KP + k] = v;
}

// ---------------- W2b: bf16 B-operand, fragment-ordered ----------------
__global__ __launch_bounds__(256) void k_packW2b(const float* __restrict__ en2w, const float* __restrict__ en2b,
                                                 u16* __restrict__ W2b){
  int idx = blockIdx.x*256 + threadIdx.x;
  if(idx >= 8*NPRIME*8) return;
  int j  = idx & 7;
  int np = (idx >> 3) % NPRIME;
  int Kc = idx / (NPRIME*8);
  int i  = Kc*8 + j;
  int o  = np / SKK, kk = np % SKK;
  float v = 0.f;
  if(kk < 64)       v = en2w[((size_t)(i*64+o))*64 + kk];
  else if(kk == 64) v = en2b[i*64+o];
  W2b[idx] = f2b(v);
}

// ---------------- packed coalesced weights for k_node ----------------
__global__ __launch_bounds__(256) void k_packRoot(const float* __restrict__ root, float4* __restrict__ rootP){
  int idx = blockIdx.x*256 + threadIdx.x;
  if(idx >= 1024) return;
  int o = idx & 63, j4 = idx >> 6;
  float4 v;
  v.x = root[(4*j4+0)*64 + o];
  v.y = root[(4*j4+1)*64 + o];
  v.z = root[(4*j4+2)*64 + o];
  v.w = root[(4*j4+3)*64 + o];
  rootP[idx] = v;
}

__global__ __launch_bounds__(256) void k_packGates(const float* __restrict__ wih, const float* __restrict__ whh,
                                                   float4* __restrict__ wihP, float4* __restrict__ whhP){
  int idx = blockIdx.x*256 + threadIdx.x;
  if(idx >= 3072) return;
  int o = idx & 63, j4 = (idx >> 6) & 15, g = idx >> 10;
  int row = (g*64 + o)*64 + 4*j4;
  float4 a, b;
  a.x = wih[row+0]; a.y = wih[row+1]; a.z = wih[row+2]; a.w = wih[row+3];
  b.x = whh[row+0]; b.y = whh[row+1]; b.z = whh[row+2]; b.w = whh[row+3];
  wihP[idx] = a; whhP[idx] = b;
}

// ---------------- packed coalesced head weights (stem s1/s2, jbond j1) ----------------
// s1P[j4*64+o]  = {s1w[o][4j4+k]}   (o = hid channel)
// s2P[j4*112+t] = {s2w[t][4j4+k]}   (t = output idx, 105 real + 7 pad)
// j1P[j4*64+k]  = {j1w[k][4j4+m]}
__global__ __launch_bounds__(256) void k_packHeads(const float* __restrict__ s1w, const float* __restrict__ s2w,
                                                   const float* __restrict__ j1w,
                                                   float4* __restrict__ s1P, float4* __restrict__ s2P,
                                                   float4* __restrict__ j1P){
  int idx = blockIdx.x*256 + threadIdx.x;
  if(idx < 1024){
    int o = idx & 63, j4 = idx >> 6;
    const float* r = s1w + o*64 + 4*j4;
    s1P[idx] = (float4){r[0], r[1], r[2], r[3]};
    const float* r2 = j1w + o*64 + 4*j4;
    j1P[idx] = (float4){r2[0], r2[1], r2[2], r2[3]};
  }
  if(idx < 1792){
    int j4 = idx / 112, t = idx % 112;
    float4 v = {0.f,0.f,0.f,0.f};
    if(t < 105){
      const float* r = s2w + t*64 + 4*j4;
      v = (float4){r[0], r[1], r[2], r[3]};
    }
    s2P[idx] = v;
  }
}

// ---------------- deg/cnt ----------------
__global__ __launch_bounds__(256) void k_degcnt(const int* __restrict__ ei,
                                                float* __restrict__ deg, int* __restrict__ cnt){
  int e = blockIdx.x*256 + threadIdx.x;
  if(e < N_EDGES){
    atomicAdd(&deg[ei[N_EDGES + e]], 1.0f);
    atomicAdd(&cnt[ei[e]], 1);
  }
}

// ---------------- scan (offs extended through PADN) ----------------
__global__ __launch_bounds__(1024) void k_scan(const int* __restrict__ cnt,
                                               int* __restrict__ offs, int* __restrict__ pos){
  __shared__ int s[1024];
  int t = threadIdx.x;
  int base = t*15;
  int c[15];
  int loc = 0;
  #pragma unroll
  for(int i=0;i<15;i++){ int idx=base+i; int v=(idx<N_NODES)?cnt[idx]:0; c[i]=v; loc+=v; }
  s[t]=loc; __syncthreads();
  for(int d=1; d<1024; d<<=1){
    int v2 = (t>=d)? s[t-d] : 0;
    __syncthreads();
    s[t] += v2;
    __syncthreads();
  }
  int run = s[t]-loc;
  #pragma unroll
  for(int i=0;i<15;i++){
    int idx=base+i;
    if(idx<N_NODES){ offs[idx]=run; pos[idx]=run; }
    run += c[i];
  }
  if(t==1023){
    for(int idx=N_NODES; idx<=PADN; idx++) offs[idx] = s[1023];
  }
}

// ---------------- CSR fill ----------------
__global__ __launch_bounds__(256) void k_fill(const int* __restrict__ ei,
                                              int* __restrict__ pos, int* __restrict__ eidx){
  int e = blockIdx.x*256 + threadIdx.x;
  if(e < N_EDGES){
    int slot = atomicAdd(&pos[ei[e]], 1);
    eidx[slot] = e;
  }
}

// ---------------- fused v3: 16-node MFMA M-build + conflict-free Ml + edge scatter ----------------
__global__ __launch_bounds__(512, 1) void k_fused(const float* __restrict__ outF, const float* __restrict__ a1,
                                               const u16* __restrict__ W2b,
                                               const int* __restrict__ ei,
                                               const int* __restrict__ offs, const int* __restrict__ eidx,
                                               float* __restrict__ agg){
  int l = threadIdx.x & 63;      // lane
  int w = threadIdx.x >> 6;      // wave 0..7
  int nb = blockIdx.x * NODESB;
  __shared__ float outs[NODESB][64];
  __shared__ u16 Ml[NODESB*NSTR];   // 139,392 B

  {
    int t = threadIdx.x;
    #pragma unroll
    for(int r=0;r<2;r++){
      int idx = t + r*512;
      outs[idx>>6][idx&63] = outF[(size_t)(nb + (idx>>6))*64 + (idx&63)];
    }
  }
  __syncthreads();

  int m = l & 15, q = l >> 4;
  frag8 afrag[2];
  #pragma unroll
  for(int f=0; f<2; f++){
    #pragma unroll
    for(int j=0;j<8;j++){
      afrag[f][j] = (short)f2b(outs[m][f*32 + q*8 + j]);
    }
  }

  facc4 acc[TILES];
  #pragma unroll
  for(int tt=0;tt<TILES;tt++) acc[tt] = (facc4){0.f,0.f,0.f,0.f};

  int nbase = w * (NPRIME/8);
  #pragma unroll
  for(int tt=0; tt<TILES; tt++){
    int np = nbase + tt*16 + m;
    frag8 b0 = *(const frag8*)(W2b + ((size_t)q      *NPRIME + np)*8);
    frag8 b1 = *(const frag8*)(W2b + ((size_t)(q + 4)*NPRIME + np)*8);
    acc[tt] = __builtin_amdgcn_mfma_f32_16x16x32_bf16(afrag[0], b0, acc[tt], 0,0,0);
    acc[tt] = __builtin_amdgcn_mfma_f32_16x16x32_bf16(afrag[1], b1, acc[tt], 0,0,0);
  }

  #pragma unroll
  for(int tt=0;tt<TILES;tt++){
    int np = nbase + tt*16 + m;
    int o = np / SKK, kk = np % SKK;
    #pragma unroll
    for(int r=0;r<4;r++){
      int mr = q*4 + r;
      Ml[mr*NSTR + o*SKK + kk] = f2b(acc[tt][r]);
    }
  }
  __syncthreads();

  int lo = offs[nb], hi = offs[nb+NODESB];
  for(int s = lo + w; s < hi; s += 8){
    int e = eidx[s];
    int src = ei[e], dst = ei[N_EDGES + e];
    int nl = src - nb;
    const float4*   ap = (const float4*)(a1 + (size_t)e*KP);
    const ushort4*  mp = (const ushort4*)(Ml + (size_t)nl*NSTR + l*SKK);
    float p = 0.f;
    #pragma unroll
    for(int qq=0; qq<17; qq++){
      float4 a4 = ap[qq];
      ushort4 m4 = mp[qq];
      p += a4.x*u2f(m4.x) + a4.y*u2f(m4.y) + a4.z*u2f(m4.z) + a4.w*u2f(m4.w);
    }
    atomicAdd(&agg[(size_t)dst*64 + l], p);
  }
}

// ---------------- node update v7: 8 nodes/512-thread block; zeroes agg for next iter ----------------
__global__ __launch_bounds__(512, 2) void k_node(float* __restrict__ agg, const float* __restrict__ deg,
                                              float* __restrict__ outF,
                                              const float4* __restrict__ rootP, const float* __restrict__ convb,
                                              const float4* __restrict__ wihP, const float4* __restrict__ whhP,
                                              const float* __restrict__ bih, const float* __restrict__ bhh){
  int o = threadIdx.x & 63, g = threadIdx.x >> 6;   // g 0..7
  int n = blockIdx.x * 8 + g;
  __shared__ __align__(16) float outs[8][64], ms[8][64];
  outs[g][o] = outF[(size_t)n*64+o];
  __syncthreads();

  const float4* op = (const float4*)outs[g];
  float acc = agg[(size_t)n*64+o] / fmaxf(deg[n], 1.0f) + convb[o];
  agg[(size_t)n*64+o] = 0.f;       // reset for next iteration (same thread owns this slot)
  #pragma unroll 8
  for(int j4=0;j4<16;j4++){
    float4 w = rootP[j4*64+o];
    float4 m = op[j4];
    acc += w.x*m.x + w.y*m.y + w.z*m.z + w.w*m.w;
  }
  ms[g][o] = lrelu(acc);
  __syncthreads();

  float ir = bih[o], iz = bih[64+o], in_ = bih[128+o];
  float hr = bhh[o], hz = bhh[64+o], hn  = bhh[128+o];
  const float4* mp = (const float4*)ms[g];
  #pragma unroll 4
  for(int j4=0;j4<16;j4++){
    float4 m4 = mp[j4], h4 = op[j4];
    float4 a;
    a = wihP[(0*16+j4)*64+o]; ir  += m4.x*a.x+m4.y*a.y+m4.z*a.z+m4.w*a.w;
    a = wihP[(1*16+j4)*64+o]; iz  += m4.x*a.x+m4.y*a.y+m4.z*a.z+m4.w*a.w;
    a = wihP[(2*16+j4)*64+o]; in_ += m4.x*a.x+m4.y*a.y+m4.z*a.z+m4.w*a.w;
    a = whhP[(0*16+j4)*64+o]; hr  += h4.x*a.x+h4.y*a.y+h4.z*a.z+h4.w*a.w;
    a = whhP[(1*16+j4)*64+o]; hz  += h4.x*a.x+h4.y*a.y+h4.z*a.z+h4.w*a.w;
    a = whhP[(2*16+j4)*64+o]; hn  += h4.x*a.x+h4.y*a.y+h4.z*a.z+h4.w*a.w;
  }
  float r  = sigmoidf(ir+hr);
  float z  = sigmoidf(iz+hz);
  float ng = tanhf(in_ + r*hn);
  float hnew = (1.f - z)*ng + z*outs[g][o];
  if(n < N_NODES) outF[(size_t)n*64+o] = hnew;
}

// ---------------- stem head v2: 4 stems/block, coalesced packed weights ----------------
__global__ __launch_bounds__(512) void k_stem(const float* __restrict__ outF, const int* __restrict__ sidx,
                                              const float4* __restrict__ s1P, const float* __restrict__ s1b,
                                              const float4* __restrict__ s2P, const float* __restrict__ s2b,
                                              void* __restrict__ dout, const int* __restrict__ flag){
  int grp = threadIdx.x >> 7, t = threadIdx.x & 127;
  int s = blockIdx.x*4 + grp;
  int isf = *flag;
  __shared__ __align__(16) float xs[4][64], hid[4][64];
  int a = sidx[s];
  if(t < 64) xs[grp][t] = outF[(size_t)a*64 + t];
  __syncthreads();
  if(t < 64){
    float acc = s1b[t];
    const float4* xp = (const float4*)xs[grp];
    #pragma unroll 8
    for(int j4=0;j4<16;j4++){
      float4 w = s1P[j4*64+t];          // coalesced
      float4 x = xp[j4];                // LDS broadcast
      acc += w.x*x.x + w.y*x.y + w.z*x.z + w.w*x.w;
    }
    hid[grp][t] = lrelu(acc);
  }
  __syncthreads();
  if(t < 105){
    float acc = s2b[t];
    const float4* hp = (const float4*)hid[grp];
    #pragma unroll 8
    for(int j4=0;j4<16;j4++){
      float4 w = s2P[j4*112+t];         // coalesced
      float4 h = hp[j4];
      acc += w.x*h.x + w.y*h.y + w.z*h.z + w.w*h.w;
    }
    store_out(dout, isf, OUT_STEM + s*105 + t, acc);
  }
}

// ---------------- jbond head v2: 4 jbonds/block, coalesced packed j1 ----------------
__global__ __launch_bounds__(512) void k_jbond(const float* __restrict__ outF, const int* __restrict__ jidx,
                                               const float4* __restrict__ j1P, const float* __restrict__ j1b,
                                               const float* __restrict__ j2w, const float* __restrict__ j2b,
                                               void* __restrict__ dout, const int* __restrict__ flag){
  int grp = threadIdx.x >> 7, t = threadIdx.x & 127;
  int jb = blockIdx.x*4 + grp;
  int isf = *flag;
  __shared__ __align__(16) float xs[4][2][64], hid[4][2][64];
  int at = t >> 6, k = t & 63;
  int a = jidx[jb*2 + at];
  xs[grp][at][k] = outF[(size_t)a*64 + k];
  __syncthreads();
  {
    float acc = j1b[k];
    const float4* xp = (const float4*)xs[grp][at];
    #pragma unroll 8
    for(int j4=0;j4<16;j4++){
      float4 w = j1P[j4*64+k];
      float4 x = xp[j4];
      acc += w.x*x.x + w.y*x.y + w.z*x.z + w.w*x.w;
    }
    hid[grp][at][k] = lrelu(acc);
  }
  __syncthreads();
  if(t < 64){
    float p = (hid[grp][0][t] + hid[grp][1][t]) * j2w[t];
    #pragma unroll
    for(int s=32;s;s>>=1) p += __shfl_xor(p, s, 64);
    if(t==0) store_out(dout, isf, OUT_JB + jb, 0.5f*p + j2b[0]);
  }
}

// ---------------- Set2Set + final linear ----------------
__global__ __launch_bounds__(64) void k_s2s(const float* __restrict__ outF, const int* __restrict__ batch,
                                            const float* __restrict__ bih, const float* __restrict__ bhh,
                                            const float* __restrict__ loutw, const float* __restrict__ loutb,
                                            void* __restrict__ dout, const int* __restrict__ flag){
  int b = blockIdx.x, t = threadIdx.x;
  int isf = *flag;
  float i_ = bih[t]     + bhh[t];
  float g_ = bih[128+t] + bhh[128+t];
  float o_ = bih[192+t] + bhh[192+t];
  float c  = sigmoidf(i_)*tanhf(g_);
  float q  = sigmoidf(o_)*tanhf(c);

  int lo = lower_bound_i(batch, N_NODES, b);
  int hi = lower_bound_i(batch, N_NODES, b+1);

  float emax = -3.4e38f;
  for(int n=lo;n<hi;n++){
    float p = outF[n*64+t]*q;
    #pragma unroll
    for(int s=32;s;s>>=1) p += __shfl_xor(p, s, 64);
    emax = fmaxf(emax, p);
  }
  float Z = 0.f, racc = 0.f;
  for(int n=lo;n<hi;n++){
    float v = outF[n*64+t];
    float p = v*q;
    #pragma unroll
    for(int s=32;s;s>>=1) p += __shfl_xor(p, s, 64);
    float w = expf(p - emax);
    Z += w; racc += w*v;
  }
  float rp = (hi>lo) ? racc/Z : 0.f;

  #pragma unroll
  for(int j=0;j<2;j++){
    float p = q*loutw[j*128+t] + rp*loutw[j*128+64+t];
    #pragma unroll
    for(int s=32;s;s>>=1) p += __shfl_xor(p, s, 64);
    if(t==0) store_out(dout, isf, OUT_FINAL + b*2 + j, p + loutb[j]);
  }
}

extern "C" void kernel_launch(void* const* d_in, const int* in_sizes, int n_in,
                              void* d_out, int out_size, void* d_ws, size_t ws_size,
                              hipStream_t stream) {
  const int* edge_index  = (const int*)d_in[28];
  const int* stem_atmidx = (const int*)d_in[29];
  const int* jbond_atmidx= (const int*)d_in[30];
  const int* batch       = (const int*)d_in[31];

  char* ws = (char*)d_ws;
  size_t off = 0;
  auto alloc = [&](size_t bytes)->void*{ void* p = ws + off; off = (off + bytes + 255) & ~(size_t)255; return p; };

  int*   flag = (int*)  alloc(4);
  float* outF = (float*)alloc((size_t)PADN*64*4);
  float* agg  = (float*)alloc((size_t)PADN*64*4);
  float* a1   = (float*)alloc((size_t)N_EDGES*KP*4);
  u16*   W2b  = (u16*)  alloc((size_t)8*NPRIME*8*2);     // 540 KB bf16 B operand
  float* deg  = (float*)alloc((size_t)PADN*4);
  int*   cnt  = (int*)  alloc((size_t)N_NODES*4);
  int*   offs = (int*)  alloc((size_t)(PADN+1)*4);
  int*   pos  = (int*)  alloc((size_t)N_NODES*4);
  int*   eidx = (int*)  alloc((size_t)N_EDGES*4);
  float4* rootP = (float4*)alloc(1024*16);
  float4* wihP  = (float4*)alloc(3072*16);
  float4* whhP  = (float4*)alloc(3072*16);
  float4* s1P   = (float4*)alloc(1024*16);
  float4* s2P   = (float4*)alloc(1792*16);
  float4* j1P   = (float4*)alloc(1024*16);

  static const int cvt_idx[N_CVT] = {0,1,2,3,4,5,6,7,8,9,10,11,12,13,14,15,16,17,18,19,20,21,24,25,26,27};
  CvtArgs A;
  float* cF[N_CVT];
  for(int i=0;i<N_CVT;i++){
    int src = cvt_idx[i];
    int n = in_sizes[src];
    cF[i] = (float*)alloc((size_t)n*4);
    A.src[i] = d_in[src];
    A.dst[i] = cF[i];
    A.n[i]   = n;
  }
  (void)ws_size; (void)n_in; (void)out_size;
  float* xF=cF[0];   float* eaF=cF[1];  float* l0w=cF[2];  float* l0b=cF[3];
  float* e1w=cF[4];  float* e1b=cF[5];  float* e2w=cF[6];  float* e2b=cF[7];
  float* rootw=cF[8];float* convb=cF[9];
  float* wih=cF[10]; float* whh=cF[11]; float* bih=cF[12]; float* bhh=cF[13];
  float* s1w=cF[14]; float* s1b=cF[15]; float* s2w=cF[16]; float* s2b=cF[17];
  float* j1w=cF[18]; float* j1b=cF[19]; float* j2w=cF[20]; float* j2b=cF[21];
  float* lbih=cF[22];float* lbhh=cF[23];float* loutw=cF[24];float* loutb=cF[25];

  hipMemsetAsync(flag, 0, 4, stream);
  hipMemsetAsync(deg,  0, (size_t)PADN*4, stream);
  hipMemsetAsync(cnt,  0, (size_t)N_NODES*4, stream);
  hipMemsetAsync(outF + (size_t)N_NODES*64, 0, (size_t)(PADN-N_NODES)*64*4, stream);
  hipMemsetAsync(agg,  0, (size_t)PADN*64*4, stream);   // once; k_node re-zeroes per iter

  k_sniff <<<128, 256, 0, stream>>>((const u16*)d_in[0], in_sizes[0], flag);
  k_cvt   <<<512, 256, 0, stream>>>(A, flag);

  k_lin0    <<<N_NODES, 64, 0, stream>>>(xF, l0w, l0b, outF);
  k_a1      <<<N_EDGES, 128, 0, stream>>>(eaF, e1w, e1b, a1);
  k_packW2b <<<(8*NPRIME*8+255)/256, 256, 0, stream>>>(e2w, e2b, W2b);
  k_packRoot<<<4, 256, 0, stream>>>(rootw, rootP);
  k_packGates<<<12, 256, 0, stream>>>(wih, whh, wihP, whhP);
  k_packHeads<<<7, 256, 0, stream>>>(s1w, s2w, j1w, s1P, s2P, j1P);
  k_degcnt  <<<(N_EDGES+255)/256, 256, 0, stream>>>(edge_index, deg, cnt);
  k_scan    <<<1, 1024, 0, stream>>>(cnt, offs, pos);
  k_fill    <<<(N_EDGES+255)/256, 256, 0, stream>>>(edge_index, pos, eidx);

  for(int it=0; it<6; it++){
    k_fused<<<PADN/NODESB, 512, 0, stream>>>(outF, a1, W2b, edge_index, offs, eidx, agg);
    k_node <<<PADN/8, 512, 0, stream>>>(agg, deg, outF, rootP, convb, wihP, whhP, bih, bhh);
  }

  k_stem <<<N_STEMS/4, 512, 0, stream>>>(outF, stem_atmidx, s1P, s1b, s2P, s2b, d_out, flag);
  k_jbond<<<N_JBONDS/4, 512, 0, stream>>>(outF, jbond_atmidx, j1P, j1b, j2w, j2b, d_out, flag);
  k_s2s  <<<NUM_GRAPHS, 64, 0, stream>>>(outF, batch, lbih, lbhh, loutw, loutb, d_out, flag);
}